// Round 1
// baseline (1738.058 us; speedup 1.0000x reference)
//
#include <hip/hip_runtime.h>
#include <cstdint>
#include <cstddef>

constexpr int F_IN  = 512;
constexpr int D_EMB = 128;
constexpr int D_HID = 64;
constexpr int N_CLS = 32;

// ---------------- lin1: H1 = relu(X @ W1 + b1)  [n,512]@[512,128] ----------
__global__ __launch_bounds__(256) void lin1_kernel(
    const float* __restrict__ X, const float* __restrict__ W1,
    const float* __restrict__ b1, float* __restrict__ H1, int n)
{
  __shared__ float Xs[64][68];    // [node][k], pad 68 to break bank strides
  __shared__ float Ws[64][128];   // [k][col]
  const int t = threadIdx.x;
  const int node0 = blockIdx.x * 64;
  const int rg = t >> 4, cg = t & 15;   // 4 rows x (4+4) cols per thread

  float acc[4][8];
#pragma unroll
  for (int i = 0; i < 4; ++i)
#pragma unroll
    for (int j = 0; j < 8; ++j) acc[i][j] = 0.f;

  for (int kc = 0; kc < F_IN; kc += 64) {
    __syncthreads();
#pragma unroll
    for (int i = 0; i < 4; ++i) {
      int lin = t + i * 256;                 // 0..1023
      int node = lin >> 4, kq = lin & 15;
      float4 v = make_float4(0.f, 0.f, 0.f, 0.f);
      if (node0 + node < n)
        v = *(const float4*)&X[(size_t)(node0 + node) * F_IN + kc + kq * 4];
      *(float4*)&Xs[node][kq * 4] = v;
    }
#pragma unroll
    for (int i = 0; i < 8; ++i) {
      int lin = t + i * 256;                 // 0..2047
      int k = lin >> 5, c4 = lin & 31;
      *(float4*)&Ws[k][c4 * 4] =
          *(const float4*)&W1[(size_t)(kc + k) * D_EMB + c4 * 4];
    }
    __syncthreads();
#pragma unroll 8
    for (int k = 0; k < 64; ++k) {
      float a[4] = {Xs[rg*4+0][k], Xs[rg*4+1][k], Xs[rg*4+2][k], Xs[rg*4+3][k]};
      float4 bA = *(const float4*)&Ws[k][cg * 4];
      float4 bB = *(const float4*)&Ws[k][64 + cg * 4];
#pragma unroll
      for (int i = 0; i < 4; ++i) {
        acc[i][0] += a[i]*bA.x; acc[i][1] += a[i]*bA.y;
        acc[i][2] += a[i]*bA.z; acc[i][3] += a[i]*bA.w;
        acc[i][4] += a[i]*bB.x; acc[i][5] += a[i]*bB.y;
        acc[i][6] += a[i]*bB.z; acc[i][7] += a[i]*bB.w;
      }
    }
  }
  float4 bb0 = *(const float4*)&b1[cg * 4];
  float4 bb1 = *(const float4*)&b1[64 + cg * 4];
#pragma unroll
  for (int i = 0; i < 4; ++i) {
    int gn = node0 + rg * 4 + i;
    if (gn < n) {
      float4 o0, o1;
      o0.x = fmaxf(acc[i][0] + bb0.x, 0.f);
      o0.y = fmaxf(acc[i][1] + bb0.y, 0.f);
      o0.z = fmaxf(acc[i][2] + bb0.z, 0.f);
      o0.w = fmaxf(acc[i][3] + bb0.w, 0.f);
      o1.x = fmaxf(acc[i][4] + bb1.x, 0.f);
      o1.y = fmaxf(acc[i][5] + bb1.y, 0.f);
      o1.z = fmaxf(acc[i][6] + bb1.z, 0.f);
      o1.w = fmaxf(acc[i][7] + bb1.w, 0.f);
      *(float4*)&H1[(size_t)gn * D_EMB + cg * 4] = o0;
      *(float4*)&H1[(size_t)gn * D_EMB + 64 + cg * 4] = o1;
    }
  }
}

// -------- mm: Out[n,64] = f(In[n,K]) @ W[K,64] ------------------------------
// PRE: input element = relu(In/deg + bin[k])  (post-aggregation epilogue of
// the previous conv, applied lazily here so aggregation stays a pure sum)
template<int K, bool PRE>
__global__ __launch_bounds__(256) void mm_kernel(
    const float* __restrict__ In, const float* __restrict__ deg,
    const float* __restrict__ bin, const float* __restrict__ W,
    float* __restrict__ Out, int n)
{
  __shared__ float Hs[64][K + 4];
  __shared__ float Ws[K][64];
  const int t = threadIdx.x;
  const int node0 = blockIdx.x * 64;
  constexpr int KQ = K / 4;

#pragma unroll
  for (int i = 0; i < (64 * KQ) / 256; ++i) {
    int lin = t + i * 256;
    int node = lin / KQ, kq = lin % KQ;
    int gn = node0 + node;
    float4 v = make_float4(0.f, 0.f, 0.f, 0.f);
    if (gn < n) {
      v = *(const float4*)&In[(size_t)gn * K + kq * 4];
      if (PRE) {
        float rd = 1.f / fmaxf(deg[gn], 1.f);
        v.x = fmaxf(v.x * rd + bin[kq * 4 + 0], 0.f);
        v.y = fmaxf(v.y * rd + bin[kq * 4 + 1], 0.f);
        v.z = fmaxf(v.z * rd + bin[kq * 4 + 2], 0.f);
        v.w = fmaxf(v.w * rd + bin[kq * 4 + 3], 0.f);
      }
    }
    *(float4*)&Hs[node][kq * 4] = v;
  }
#pragma unroll
  for (int i = 0; i < (K * 64) / 1024; ++i) {
    int lin = t + i * 256;
    ((float4*)&Ws[0][0])[lin] = ((const float4*)W)[lin];
  }
  __syncthreads();

  const int rg = t >> 4, cg = t & 15;
  float acc[4][4];
#pragma unroll
  for (int i = 0; i < 4; ++i)
#pragma unroll
    for (int j = 0; j < 4; ++j) acc[i][j] = 0.f;

#pragma unroll 8
  for (int k = 0; k < K; ++k) {
    float a[4] = {Hs[rg*4+0][k], Hs[rg*4+1][k], Hs[rg*4+2][k], Hs[rg*4+3][k]};
    float4 b = *(const float4*)&Ws[k][cg * 4];
#pragma unroll
    for (int i = 0; i < 4; ++i) {
      acc[i][0] += a[i]*b.x; acc[i][1] += a[i]*b.y;
      acc[i][2] += a[i]*b.z; acc[i][3] += a[i]*b.w;
    }
  }
#pragma unroll
  for (int i = 0; i < 4; ++i) {
    int gn = node0 + rg * 4 + i;
    if (gn < n) {
      float4 o = make_float4(acc[i][0], acc[i][1], acc[i][2], acc[i][3]);
      *(float4*)&Out[(size_t)gn * 64 + cg * 4] = o;
    }
  }
}

// ---------------- degree ----------------------------------------------------
__global__ __launch_bounds__(256) void deg_kernel(
    const int* __restrict__ dst, float* __restrict__ deg, int nE)
{
  int e = blockIdx.x * 256 + threadIdx.x;
  if (e < nE) atomicAdd(&deg[dst[e]], 1.f);
}

// ---------------- scatter: A[dst] += P[src]  (64 feats/edge) ----------------
__global__ __launch_bounds__(256) void scatter_kernel(
    const float* __restrict__ P, const int* __restrict__ src,
    const int* __restrict__ dst, float* __restrict__ A, int nE)
{
  long long g = (long long)blockIdx.x * 256 + threadIdx.x;
  int e = (int)(g >> 6), f = (int)(g & 63);
  if (e < nE) {
    int s = src[e], d = dst[e];
    atomicAdd(&A[(size_t)d * 64 + f], P[(size_t)s * 64 + f]);
  }
}

// ---- conv3 epilogue: H4 = relu(A/deg + bc3); accumulate sum/sumsq ----------
__global__ __launch_bounds__(256) void post3_kernel(
    const float* __restrict__ A, const float* __restrict__ deg,
    const float* __restrict__ bc3, float* __restrict__ H4,
    float* __restrict__ stats, int n)
{
  int t = threadIdx.x;
  int f = t & 63, q = t >> 6;
  float b = bc3[f];
  float s = 0.f, s2 = 0.f;
  for (int node = blockIdx.x * 4 + q; node < n; node += gridDim.x * 4) {
    float v = fmaxf(A[(size_t)node * 64 + f] / fmaxf(deg[node], 1.f) + b, 0.f);
    H4[(size_t)node * 64 + f] = v;
    s += v; s2 += v * v;
  }
  __shared__ float red[2][4][64];
  red[0][q][f] = s; red[1][q][f] = s2;
  __syncthreads();
  if (t < 128) {
    int which = t >> 6, ff = t & 63;
    float a = red[which][0][ff] + red[which][1][ff] +
              red[which][2][ff] + red[which][3][ff];
    atomicAdd(&stats[which * 64 + ff], a);
  }
}

// ---- fold batchnorm into W2: W2f = diag(rs*gamma)W2, b2f = b2+(beta-mu*rs*g)W2
__global__ __launch_bounds__(256) void fold_kernel(
    const float* __restrict__ stats, const float* __restrict__ gamma,
    const float* __restrict__ beta, const float* __restrict__ W2,
    const float* __restrict__ b2, float* __restrict__ W2f,
    float* __restrict__ b2f, int n)
{
  __shared__ float rsg[64], corr[64];
  int t = threadIdx.x;
  if (t < 64) {
    float m = stats[t] / (float)n;
    float var = stats[64 + t] / (float)n - m * m;
    float rs = rsqrtf(var + 1e-5f);
    float g = gamma[t] * rs;
    rsg[t] = g;
    corr[t] = beta[t] - m * g;
  }
  __syncthreads();
#pragma unroll
  for (int i = 0; i < 8; ++i) {
    int lin = t + i * 256;          // 0..2047
    int k = lin >> 5;
    W2f[lin] = rsg[k] * W2[lin];
  }
  if (t < 32) {
    float a = b2[t];
    for (int k = 0; k < 64; ++k) a += corr[k] * W2[k * 32 + t];
    b2f[t] = a;
  }
}

// ---- final: out = relu(H4 @ W2f + b2f) @ W3 + b3 ---------------------------
__global__ __launch_bounds__(256) void final_kernel(
    const float* __restrict__ H4, const float* __restrict__ W2f,
    const float* __restrict__ b2f, const float* __restrict__ W3,
    const float* __restrict__ b3, float* __restrict__ Out, int n)
{
  __shared__ float Hs[64][68];
  __shared__ float W2s[64][32];
  __shared__ float W3s[32][32];
  __shared__ float Us[64][36];
  __shared__ float b2s[32], b3s[32];
  const int t = threadIdx.x;
  const int node0 = blockIdx.x * 64;

#pragma unroll
  for (int i = 0; i < 4; ++i) {
    int lin = t + i * 256;
    int node = lin >> 4, kq = lin & 15;
    float4 v = make_float4(0.f, 0.f, 0.f, 0.f);
    if (node0 + node < n)
      v = *(const float4*)&H4[(size_t)(node0 + node) * 64 + kq * 4];
    *(float4*)&Hs[node][kq * 4] = v;
  }
#pragma unroll
  for (int i = 0; i < 2; ++i) {
    int lin = t + i * 256;          // 512 float4 = 2048 floats
    ((float4*)&W2s[0][0])[lin] = ((const float4*)W2f)[lin];
  }
  ((float4*)&W3s[0][0])[t & 255] = ((const float4*)W3)[t & 255];
  if (t < 32) { b2s[t] = b2f[t]; b3s[t] = b3[t]; }
  __syncthreads();

  const int rg = t >> 4, cg = t & 15;   // 4 rows x 2 cols (of 32)
  float acc[4][2] = {{0.f,0.f},{0.f,0.f},{0.f,0.f},{0.f,0.f}};
#pragma unroll 8
  for (int k = 0; k < 64; ++k) {
    float a[4] = {Hs[rg*4+0][k], Hs[rg*4+1][k], Hs[rg*4+2][k], Hs[rg*4+3][k]};
    float w0 = W2s[k][cg*2], w1 = W2s[k][cg*2+1];
#pragma unroll
    for (int i = 0; i < 4; ++i) { acc[i][0] += a[i]*w0; acc[i][1] += a[i]*w1; }
  }
#pragma unroll
  for (int i = 0; i < 4; ++i) {
    Us[rg*4+i][cg*2+0] = fmaxf(acc[i][0] + b2s[cg*2+0], 0.f);
    Us[rg*4+i][cg*2+1] = fmaxf(acc[i][1] + b2s[cg*2+1], 0.f);
  }
  __syncthreads();

  float acc2[4][2] = {{0.f,0.f},{0.f,0.f},{0.f,0.f},{0.f,0.f}};
#pragma unroll
  for (int k = 0; k < 32; ++k) {
    float a[4] = {Us[rg*4+0][k], Us[rg*4+1][k], Us[rg*4+2][k], Us[rg*4+3][k]};
    float w0 = W3s[k][cg*2], w1 = W3s[k][cg*2+1];
#pragma unroll
    for (int i = 0; i < 4; ++i) { acc2[i][0] += a[i]*w0; acc2[i][1] += a[i]*w1; }
  }
  // stage output tile through LDS (reuse Hs) for coalesced float4 stores
  float (*Os)[36] = (float(*)[36])Hs;
#pragma unroll
  for (int i = 0; i < 4; ++i) {
    Os[rg*4+i][cg*2+0] = acc2[i][0] + b3s[cg*2+0];
    Os[rg*4+i][cg*2+1] = acc2[i][1] + b3s[cg*2+1];
  }
  __syncthreads();
#pragma unroll
  for (int i = 0; i < 2; ++i) {
    int lin = t + i * 256;          // 0..511 float4
    int node = lin >> 3, c4 = lin & 7;
    if (node0 + node < n)
      *(float4*)&Out[(size_t)(node0 + node) * 32 + c4 * 4] =
          *(float4*)&Os[node][c4 * 4];
  }
}

// ---------------------------------------------------------------------------
extern "C" void kernel_launch(void* const* d_in, const int* in_sizes, int n_in,
                              void* d_out, int out_size, void* d_ws, size_t ws_size,
                              hipStream_t stream)
{
  const float* X     = (const float*)d_in[0];
  const float* W1    = (const float*)d_in[1];
  const float* b1    = (const float*)d_in[2];
  const float* Wc1   = (const float*)d_in[3];
  const float* bc1   = (const float*)d_in[4];
  const float* Wc2   = (const float*)d_in[5];
  const float* bc2   = (const float*)d_in[6];
  const float* Wc3   = (const float*)d_in[7];
  const float* bc3   = (const float*)d_in[8];
  const float* gamma = (const float*)d_in[9];
  const float* beta  = (const float*)d_in[10];
  const float* W2    = (const float*)d_in[11];
  const float* b2    = (const float*)d_in[12];
  const float* W3    = (const float*)d_in[13];
  const float* b3    = (const float*)d_in[14];
  const int*   ei    = (const int*)d_in[15];

  const int n  = in_sizes[0] / F_IN;
  const int nE = in_sizes[15] / 2;
  const int* src  = ei;
  const int* dstv = ei + nE;

  float* ws    = (float*)d_ws;
  float* H1    = ws;                                   // n*128
  float* P     = H1 + (size_t)n * D_EMB;               // n*64
  float* A     = P  + (size_t)n * D_HID;               // n*64
  float* H4    = A  + (size_t)n * D_HID;               // n*64
  float* deg   = H4 + (size_t)n * D_HID;               // n
  float* stats = deg + n;                              // 128
  float* W2f   = stats + 128;                          // 2048
  float* b2f   = W2f + 2048;                           // 32

  const int nb = (n + 63) / 64;
  const int scatterBlocks = (int)(((long long)nE * 64 + 255) / 256);

  // zero the accumulated buffers (ws is poisoned before every call)
  hipMemsetAsync(A,   0, (size_t)n * D_HID * sizeof(float), stream);
  hipMemsetAsync(deg, 0, ((size_t)n + 128) * sizeof(float), stream);

  lin1_kernel<<<nb, 256, 0, stream>>>(X, W1, b1, H1, n);
  deg_kernel<<<(nE + 255) / 256, 256, 0, stream>>>(dstv, deg, nE);

  // conv1: P1 = H1 @ Wc1 ; A = scatter(P1)
  mm_kernel<128, false><<<nb, 256, 0, stream>>>(H1, nullptr, nullptr, Wc1, P, n);
  scatter_kernel<<<scatterBlocks, 256, 0, stream>>>(P, src, dstv, A, nE);

  // conv2: P2 = relu(A/deg + bc1) @ Wc2 ; A = scatter(P2)
  mm_kernel<64, true><<<nb, 256, 0, stream>>>(A, deg, bc1, Wc2, P, n);
  hipMemsetAsync(A, 0, (size_t)n * D_HID * sizeof(float), stream);
  scatter_kernel<<<scatterBlocks, 256, 0, stream>>>(P, src, dstv, A, nE);

  // conv3: P3 = relu(A/deg + bc2) @ Wc3 ; A = scatter(P3)
  mm_kernel<64, true><<<nb, 256, 0, stream>>>(A, deg, bc2, Wc3, P, n);
  hipMemsetAsync(A, 0, (size_t)n * D_HID * sizeof(float), stream);
  scatter_kernel<<<scatterBlocks, 256, 0, stream>>>(P, src, dstv, A, nE);

  // conv3 epilogue + batch stats
  post3_kernel<<<256, 256, 0, stream>>>(A, deg, bc3, H4, stats, n);

  // fold batchnorm into W2, then fused lin2+lin3
  fold_kernel<<<1, 256, 0, stream>>>(stats, gamma, beta, W2, b2, W2f, b2f, n);
  final_kernel<<<nb, 256, 0, stream>>>(H4, W2f, b2f, W3, b3, (float*)d_out, n);
}

// Round 2
// 1005.481 us; speedup vs baseline: 1.7286x; 1.7286x over previous
//
#include <hip/hip_runtime.h>
#include <cstdint>
#include <cstddef>

constexpr int F_IN  = 512;
constexpr int D_EMB = 128;
constexpr int D_HID = 64;
constexpr int N_CLS = 32;

// ---------------- lin1: H1 = relu(X @ W1 + b1)  [n,512]@[512,128] ----------
__global__ __launch_bounds__(256) void lin1_kernel(
    const float* __restrict__ X, const float* __restrict__ W1,
    const float* __restrict__ b1, float* __restrict__ H1, int n)
{
  __shared__ float Xs[64][68];
  __shared__ float Ws[64][128];
  const int t = threadIdx.x;
  const int node0 = blockIdx.x * 64;
  const int rg = t >> 4, cg = t & 15;

  float acc[4][8];
#pragma unroll
  for (int i = 0; i < 4; ++i)
#pragma unroll
    for (int j = 0; j < 8; ++j) acc[i][j] = 0.f;

  for (int kc = 0; kc < F_IN; kc += 64) {
    __syncthreads();
#pragma unroll
    for (int i = 0; i < 4; ++i) {
      int lin = t + i * 256;
      int node = lin >> 4, kq = lin & 15;
      float4 v = make_float4(0.f, 0.f, 0.f, 0.f);
      if (node0 + node < n)
        v = *(const float4*)&X[(size_t)(node0 + node) * F_IN + kc + kq * 4];
      *(float4*)&Xs[node][kq * 4] = v;
    }
#pragma unroll
    for (int i = 0; i < 8; ++i) {
      int lin = t + i * 256;
      int k = lin >> 5, c4 = lin & 31;
      *(float4*)&Ws[k][c4 * 4] =
          *(const float4*)&W1[(size_t)(kc + k) * D_EMB + c4 * 4];
    }
    __syncthreads();
#pragma unroll 8
    for (int k = 0; k < 64; ++k) {
      float a[4] = {Xs[rg*4+0][k], Xs[rg*4+1][k], Xs[rg*4+2][k], Xs[rg*4+3][k]};
      float4 bA = *(const float4*)&Ws[k][cg * 4];
      float4 bB = *(const float4*)&Ws[k][64 + cg * 4];
#pragma unroll
      for (int i = 0; i < 4; ++i) {
        acc[i][0] += a[i]*bA.x; acc[i][1] += a[i]*bA.y;
        acc[i][2] += a[i]*bA.z; acc[i][3] += a[i]*bA.w;
        acc[i][4] += a[i]*bB.x; acc[i][5] += a[i]*bB.y;
        acc[i][6] += a[i]*bB.z; acc[i][7] += a[i]*bB.w;
      }
    }
  }
  float4 bb0 = *(const float4*)&b1[cg * 4];
  float4 bb1 = *(const float4*)&b1[64 + cg * 4];
#pragma unroll
  for (int i = 0; i < 4; ++i) {
    int gn = node0 + rg * 4 + i;
    if (gn < n) {
      float4 o0, o1;
      o0.x = fmaxf(acc[i][0] + bb0.x, 0.f);
      o0.y = fmaxf(acc[i][1] + bb0.y, 0.f);
      o0.z = fmaxf(acc[i][2] + bb0.z, 0.f);
      o0.w = fmaxf(acc[i][3] + bb0.w, 0.f);
      o1.x = fmaxf(acc[i][4] + bb1.x, 0.f);
      o1.y = fmaxf(acc[i][5] + bb1.y, 0.f);
      o1.z = fmaxf(acc[i][6] + bb1.z, 0.f);
      o1.w = fmaxf(acc[i][7] + bb1.w, 0.f);
      *(float4*)&H1[(size_t)gn * D_EMB + cg * 4] = o0;
      *(float4*)&H1[(size_t)gn * D_EMB + 64 + cg * 4] = o1;
    }
  }
}

// -------- mm: Out[n,64] = f(In[n,K]) @ W[K,64] ------------------------------
// PRE: input element = relu(In/deg + bin[k])
template<int K, bool PRE>
__global__ __launch_bounds__(256) void mm_kernel(
    const float* __restrict__ In, const int* __restrict__ deg,
    const float* __restrict__ bin, const float* __restrict__ W,
    float* __restrict__ Out, int n)
{
  __shared__ float Hs[64][K + 4];
  __shared__ float Ws[K][64];
  const int t = threadIdx.x;
  const int node0 = blockIdx.x * 64;
  constexpr int KQ = K / 4;

#pragma unroll
  for (int i = 0; i < (64 * KQ) / 256; ++i) {
    int lin = t + i * 256;
    int node = lin / KQ, kq = lin % KQ;
    int gn = node0 + node;
    float4 v = make_float4(0.f, 0.f, 0.f, 0.f);
    if (gn < n) {
      v = *(const float4*)&In[(size_t)gn * K + kq * 4];
      if (PRE) {
        float rd = 1.f / fmaxf((float)deg[gn], 1.f);
        v.x = fmaxf(v.x * rd + bin[kq * 4 + 0], 0.f);
        v.y = fmaxf(v.y * rd + bin[kq * 4 + 1], 0.f);
        v.z = fmaxf(v.z * rd + bin[kq * 4 + 2], 0.f);
        v.w = fmaxf(v.w * rd + bin[kq * 4 + 3], 0.f);
      }
    }
    *(float4*)&Hs[node][kq * 4] = v;
  }
#pragma unroll
  for (int i = 0; i < (K * 64) / 1024; ++i) {
    int lin = t + i * 256;
    ((float4*)&Ws[0][0])[lin] = ((const float4*)W)[lin];
  }
  __syncthreads();

  const int rg = t >> 4, cg = t & 15;
  float acc[4][4];
#pragma unroll
  for (int i = 0; i < 4; ++i)
#pragma unroll
    for (int j = 0; j < 4; ++j) acc[i][j] = 0.f;

#pragma unroll 8
  for (int k = 0; k < K; ++k) {
    float a[4] = {Hs[rg*4+0][k], Hs[rg*4+1][k], Hs[rg*4+2][k], Hs[rg*4+3][k]};
    float4 b = *(const float4*)&Ws[k][cg * 4];
#pragma unroll
    for (int i = 0; i < 4; ++i) {
      acc[i][0] += a[i]*b.x; acc[i][1] += a[i]*b.y;
      acc[i][2] += a[i]*b.z; acc[i][3] += a[i]*b.w;
    }
  }
#pragma unroll
  for (int i = 0; i < 4; ++i) {
    int gn = node0 + rg * 4 + i;
    if (gn < n) {
      float4 o = make_float4(acc[i][0], acc[i][1], acc[i][2], acc[i][3]);
      *(float4*)&Out[(size_t)gn * 64 + cg * 4] = o;
    }
  }
}

// ---------------- CSR build: count, scan, fill ------------------------------
__global__ __launch_bounds__(256) void count_kernel(
    const int* __restrict__ dst, int* __restrict__ cnt, int nE)
{
  int e = blockIdx.x * 256 + threadIdx.x;
  if (e < nE) atomicAdd(&cnt[dst[e]], 1);
}

// per-block inclusive scan of 256 counts -> exclusive-in-block offs + bsum[b]
__global__ __launch_bounds__(256) void scan1_kernel(
    const int* __restrict__ cnt, int* __restrict__ offs,
    int* __restrict__ bsum, int n)
{
  __shared__ int sh[256];
  int t = threadIdx.x;
  int node = blockIdx.x * 256 + t;
  int c = (node < n) ? cnt[node] : 0;
  sh[t] = c;
  __syncthreads();
#pragma unroll
  for (int off = 1; off < 256; off <<= 1) {
    int v = 0;
    if (t >= off) v = sh[t - off];
    __syncthreads();
    if (t >= off) sh[t] += v;
    __syncthreads();
  }
  if (node < n) offs[node] = sh[t] - c;     // exclusive within block
  if (t == 255) bsum[blockIdx.x] = sh[255];
}

__global__ void scan2_kernel(int* __restrict__ bsum, int nb)
{
  // tiny serial scan (nb <= ~400)
  int run = 0;
  for (int i = 0; i < nb; ++i) { int v = bsum[i]; bsum[i] = run; run += v; }
  bsum[nb] = run;
}

__global__ __launch_bounds__(256) void scan3_kernel(
    int* __restrict__ offs, int* __restrict__ cursor,
    const int* __restrict__ bsum, int n, int nb)
{
  int i = blockIdx.x * 256 + threadIdx.x;
  if (i < n) {
    int v = offs[i] + bsum[i >> 8];
    offs[i] = v;
    cursor[i] = v;
  } else if (i == n) {
    offs[n] = bsum[nb];
  }
}

__global__ __launch_bounds__(256) void fill_kernel(
    const int* __restrict__ src, const int* __restrict__ dst,
    int* __restrict__ cursor, int* __restrict__ adj, int nE)
{
  int e = blockIdx.x * 256 + threadIdx.x;
  if (e < nE) {
    int slot = atomicAdd(&cursor[dst[e]], 1);
    adj[slot] = src[e];
  }
}

// ---------------- gather: A[d] = sum_{s in adj[d]} P[s]  (wave per node) ----
__global__ __launch_bounds__(256) void gather_kernel(
    const float* __restrict__ P, const int* __restrict__ offs,
    const int* __restrict__ adj, float* __restrict__ A, int n)
{
  int node = (blockIdx.x * 256 + threadIdx.x) >> 6;
  int lane = threadIdx.x & 63;
  if (node >= n) return;
  int beg = offs[node], end = offs[node + 1];
  float acc0 = 0.f, acc1 = 0.f;
  int j = beg;
  while (j < end) {
    int m = min(end - j, 64);
    int idx = (lane < m) ? adj[j + lane] : 0;
    int q = 0;
    for (; q + 1 < m; q += 2) {
      int s0 = __shfl(idx, q, 64);
      int s1 = __shfl(idx, q + 1, 64);
      acc0 += P[(size_t)s0 * 64 + lane];
      acc1 += P[(size_t)s1 * 64 + lane];
    }
    if (q < m) {
      int s0 = __shfl(idx, q, 64);
      acc0 += P[(size_t)s0 * 64 + lane];
    }
    j += m;
  }
  A[(size_t)node * 64 + lane] = acc0 + acc1;
}

// ---- conv3 epilogue: H4 = relu(A/deg + bc3); accumulate sum/sumsq ----------
__global__ __launch_bounds__(256) void post3_kernel(
    const float* __restrict__ A, const int* __restrict__ deg,
    const float* __restrict__ bc3, float* __restrict__ H4,
    float* __restrict__ stats, int n)
{
  int t = threadIdx.x;
  int f = t & 63, q = t >> 6;
  float b = bc3[f];
  float s = 0.f, s2 = 0.f;
  for (int node = blockIdx.x * 4 + q; node < n; node += gridDim.x * 4) {
    float v = fmaxf(A[(size_t)node * 64 + f] / fmaxf((float)deg[node], 1.f) + b, 0.f);
    H4[(size_t)node * 64 + f] = v;
    s += v; s2 += v * v;
  }
  __shared__ float red[2][4][64];
  red[0][q][f] = s; red[1][q][f] = s2;
  __syncthreads();
  if (t < 128) {
    int which = t >> 6, ff = t & 63;
    float a = red[which][0][ff] + red[which][1][ff] +
              red[which][2][ff] + red[which][3][ff];
    atomicAdd(&stats[which * 64 + ff], a);
  }
}

// ---- fold batchnorm into W2 ------------------------------------------------
__global__ __launch_bounds__(256) void fold_kernel(
    const float* __restrict__ stats, const float* __restrict__ gamma,
    const float* __restrict__ beta, const float* __restrict__ W2,
    const float* __restrict__ b2, float* __restrict__ W2f,
    float* __restrict__ b2f, int n)
{
  __shared__ float rsg[64], corr[64];
  int t = threadIdx.x;
  if (t < 64) {
    float m = stats[t] / (float)n;
    float var = stats[64 + t] / (float)n - m * m;
    float rs = rsqrtf(var + 1e-5f);
    float g = gamma[t] * rs;
    rsg[t] = g;
    corr[t] = beta[t] - m * g;
  }
  __syncthreads();
#pragma unroll
  for (int i = 0; i < 8; ++i) {
    int lin = t + i * 256;
    int k = lin >> 5;
    W2f[lin] = rsg[k] * W2[lin];
  }
  if (t < 32) {
    float a = b2[t];
    for (int k = 0; k < 64; ++k) a += corr[k] * W2[k * 32 + t];
    b2f[t] = a;
  }
}

// ---- final: out = relu(H4 @ W2f + b2f) @ W3 + b3 ---------------------------
__global__ __launch_bounds__(256) void final_kernel(
    const float* __restrict__ H4, const float* __restrict__ W2f,
    const float* __restrict__ b2f, const float* __restrict__ W3,
    const float* __restrict__ b3, float* __restrict__ Out, int n)
{
  __shared__ float Hs[64][68];
  __shared__ float W2s[64][32];
  __shared__ float W3s[32][32];
  __shared__ float Us[64][36];
  __shared__ float b2s[32], b3s[32];
  const int t = threadIdx.x;
  const int node0 = blockIdx.x * 64;

#pragma unroll
  for (int i = 0; i < 4; ++i) {
    int lin = t + i * 256;
    int node = lin >> 4, kq = lin & 15;
    float4 v = make_float4(0.f, 0.f, 0.f, 0.f);
    if (node0 + node < n)
      v = *(const float4*)&H4[(size_t)(node0 + node) * 64 + kq * 4];
    *(float4*)&Hs[node][kq * 4] = v;
  }
#pragma unroll
  for (int i = 0; i < 2; ++i) {
    int lin = t + i * 256;
    ((float4*)&W2s[0][0])[lin] = ((const float4*)W2f)[lin];
  }
  ((float4*)&W3s[0][0])[t & 255] = ((const float4*)W3)[t & 255];
  if (t < 32) { b2s[t] = b2f[t]; b3s[t] = b3[t]; }
  __syncthreads();

  const int rg = t >> 4, cg = t & 15;
  float acc[4][2] = {{0.f,0.f},{0.f,0.f},{0.f,0.f},{0.f,0.f}};
#pragma unroll 8
  for (int k = 0; k < 64; ++k) {
    float a[4] = {Hs[rg*4+0][k], Hs[rg*4+1][k], Hs[rg*4+2][k], Hs[rg*4+3][k]};
    float w0 = W2s[k][cg*2], w1 = W2s[k][cg*2+1];
#pragma unroll
    for (int i = 0; i < 4; ++i) { acc[i][0] += a[i]*w0; acc[i][1] += a[i]*w1; }
  }
#pragma unroll
  for (int i = 0; i < 4; ++i) {
    Us[rg*4+i][cg*2+0] = fmaxf(acc[i][0] + b2s[cg*2+0], 0.f);
    Us[rg*4+i][cg*2+1] = fmaxf(acc[i][1] + b2s[cg*2+1], 0.f);
  }
  __syncthreads();

  float acc2[4][2] = {{0.f,0.f},{0.f,0.f},{0.f,0.f},{0.f,0.f}};
#pragma unroll
  for (int k = 0; k < 32; ++k) {
    float a[4] = {Us[rg*4+0][k], Us[rg*4+1][k], Us[rg*4+2][k], Us[rg*4+3][k]};
    float w0 = W3s[k][cg*2], w1 = W3s[k][cg*2+1];
#pragma unroll
    for (int i = 0; i < 4; ++i) { acc2[i][0] += a[i]*w0; acc2[i][1] += a[i]*w1; }
  }
  float (*Os)[36] = (float(*)[36])Hs;
#pragma unroll
  for (int i = 0; i < 4; ++i) {
    Os[rg*4+i][cg*2+0] = acc2[i][0] + b3s[cg*2+0];
    Os[rg*4+i][cg*2+1] = acc2[i][1] + b3s[cg*2+1];
  }
  __syncthreads();
#pragma unroll
  for (int i = 0; i < 2; ++i) {
    int lin = t + i * 256;
    int node = lin >> 3, c4 = lin & 7;
    if (node0 + node < n)
      *(float4*)&Out[(size_t)(node0 + node) * 32 + c4 * 4] =
          *(float4*)&Os[node][c4 * 4];
  }
}

// ---------------------------------------------------------------------------
extern "C" void kernel_launch(void* const* d_in, const int* in_sizes, int n_in,
                              void* d_out, int out_size, void* d_ws, size_t ws_size,
                              hipStream_t stream)
{
  const float* X     = (const float*)d_in[0];
  const float* W1    = (const float*)d_in[1];
  const float* b1    = (const float*)d_in[2];
  const float* Wc1   = (const float*)d_in[3];
  const float* bc1   = (const float*)d_in[4];
  const float* Wc2   = (const float*)d_in[5];
  const float* bc2   = (const float*)d_in[6];
  const float* Wc3   = (const float*)d_in[7];
  const float* bc3   = (const float*)d_in[8];
  const float* gamma = (const float*)d_in[9];
  const float* beta  = (const float*)d_in[10];
  const float* W2    = (const float*)d_in[11];
  const float* b2    = (const float*)d_in[12];
  const float* W3    = (const float*)d_in[13];
  const float* b3    = (const float*)d_in[14];
  const int*   ei    = (const int*)d_in[15];

  const int n  = in_sizes[0] / F_IN;
  const int nE = in_sizes[15] / 2;
  const int* src  = ei;
  const int* dstv = ei + nE;

  float* ws    = (float*)d_ws;
  float* H1    = ws;                                   // n*128 (H4 reuses)
  float* P     = H1 + (size_t)n * D_EMB;               // n*64
  float* A     = P  + (size_t)n * D_HID;               // n*64
  float* stats = A  + (size_t)n * D_HID;               // 128
  float* W2f   = stats + 128;                          // 2048
  float* b2f   = W2f + 2048;                           // 32
  int*   cnt    = (int*)(b2f + 32);                    // n
  int*   offs   = cnt + n;                             // n+1
  int*   cursor = offs + n + 1;                        // n
  int*   bsum   = cursor + n;                          // 512
  int*   adj    = bsum + 512;                          // nE
  float* H4    = H1;                                   // reuse H1 (dead after conv1 mm)

  const int nb  = (n + 63) / 64;
  const int nb2 = (n + 255) / 256;
  const int eb  = (nE + 255) / 256;
  const int gatherBlocks = (int)(((long long)n * 64 + 255) / 256);

  hipMemsetAsync(cnt,   0, (size_t)n * sizeof(int), stream);
  hipMemsetAsync(stats, 0, 128 * sizeof(float), stream);

  lin1_kernel<<<nb, 256, 0, stream>>>(X, W1, b1, H1, n);

  // CSR build
  count_kernel<<<eb, 256, 0, stream>>>(dstv, cnt, nE);
  scan1_kernel<<<nb2, 256, 0, stream>>>(cnt, offs, bsum, n);
  scan2_kernel<<<1, 1, 0, stream>>>(bsum, nb2);
  scan3_kernel<<<(n + 256) / 256, 256, 0, stream>>>(offs, cursor, bsum, n, nb2);
  fill_kernel<<<eb, 256, 0, stream>>>(src, dstv, cursor, adj, nE);

  // conv1: P = H1 @ Wc1 ; A = gather-sum(P)
  mm_kernel<128, false><<<nb, 256, 0, stream>>>(H1, nullptr, nullptr, Wc1, P, n);
  gather_kernel<<<gatherBlocks, 256, 0, stream>>>(P, offs, adj, A, n);

  // conv2
  mm_kernel<64, true><<<nb, 256, 0, stream>>>(A, cnt, bc1, Wc2, P, n);
  gather_kernel<<<gatherBlocks, 256, 0, stream>>>(P, offs, adj, A, n);

  // conv3
  mm_kernel<64, true><<<nb, 256, 0, stream>>>(A, cnt, bc2, Wc3, P, n);
  gather_kernel<<<gatherBlocks, 256, 0, stream>>>(P, offs, adj, A, n);

  // conv3 epilogue + batch stats
  post3_kernel<<<256, 256, 0, stream>>>(A, cnt, bc3, H4, stats, n);

  // fold batchnorm into W2, then fused lin2+lin3
  fold_kernel<<<1, 256, 0, stream>>>(stats, gamma, beta, W2, b2, W2f, b2f, n);
  final_kernel<<<nb, 256, 0, stream>>>(H4, W2f, b2f, W3, b3, (float*)d_out, n);
}

// Round 3
// 915.758 us; speedup vs baseline: 1.8979x; 1.0980x over previous
//
#include <hip/hip_runtime.h>
#include <cstdint>
#include <cstddef>

constexpr int F_IN  = 512;
constexpr int D_EMB = 128;
constexpr int D_HID = 64;
constexpr int N_CLS = 32;

typedef __attribute__((ext_vector_type(8))) short short8;
typedef __attribute__((ext_vector_type(4))) float floatx4;

__device__ inline unsigned short f2bf(float f) {
  union { float f; uint32_t u; } v; v.f = f;
  uint32_t r = v.u + 0x7FFF + ((v.u >> 16) & 1);   // round-to-nearest-even
  return (unsigned short)(r >> 16);
}

// ---- W1 pre-transpose+convert: Wt[col][k] bf16, col<128, k<512 -------------
__global__ __launch_bounds__(256) void wt_kernel(
    const float* __restrict__ W1, unsigned short* __restrict__ Wt)
{
  int idx = blockIdx.x * 256 + threadIdx.x;     // 65536
  int col = idx >> 9, k = idx & 511;
  Wt[idx] = f2bf(W1[(size_t)k * D_EMB + col]);
}

// ---- lin1 MFMA: H1 = relu(X @ W1 + b1), bf16 inputs, fp32 out --------------
// block: 128 rows x 128 cols, 4 waves (2x2), wave = 64x64 via 16x16x32 bf16
__global__ __launch_bounds__(256) void lin1_mfma_kernel(
    const float* __restrict__ X, const unsigned short* __restrict__ Wt,
    const float* __restrict__ b1, float* __restrict__ H1, int n)
{
  constexpr int XP = 72;                        // LDS pitch in bf16 (16B aligned)
  __shared__ __align__(16) unsigned short Xs[128 * XP];
  __shared__ __align__(16) unsigned short Ws[128 * XP];

  const int t = threadIdx.x;
  const int wave = t >> 6, lane = t & 63;
  const int quad = lane >> 4, mrow = lane & 15;
  const int node0 = blockIdx.x * 128;
  const int rowbase = (wave >> 1) * 64;
  const int colbase = (wave & 1) * 64;

  floatx4 acc[4][4];
#pragma unroll
  for (int i = 0; i < 4; ++i)
#pragma unroll
    for (int j = 0; j < 4; ++j) acc[i][j] = (floatx4){0.f, 0.f, 0.f, 0.f};

  for (int kc = 0; kc < F_IN; kc += 64) {
    __syncthreads();
    // stage X[node0..+128][kc..+64] fp32 -> bf16 LDS
#pragma unroll
    for (int i = 0; i < 4; ++i) {
      int lin = t + i * 256;                    // 0..1023
      int row = lin >> 3, seg = lin & 7;        // seg = 8 k's
      int gn = node0 + row;
      float4 v0 = make_float4(0.f, 0.f, 0.f, 0.f);
      float4 v1 = make_float4(0.f, 0.f, 0.f, 0.f);
      if (gn < n) {
        const float* p = &X[(size_t)gn * F_IN + kc + seg * 8];
        v0 = *(const float4*)p;
        v1 = *(const float4*)(p + 4);
      }
      short8 s;
      s[0] = (short)f2bf(v0.x); s[1] = (short)f2bf(v0.y);
      s[2] = (short)f2bf(v0.z); s[3] = (short)f2bf(v0.w);
      s[4] = (short)f2bf(v1.x); s[5] = (short)f2bf(v1.y);
      s[6] = (short)f2bf(v1.z); s[7] = (short)f2bf(v1.w);
      *(short8*)&Xs[row * XP + seg * 8] = s;
    }
    // stage Wt[0..128][kc..+64] bf16 -> LDS (already transposed: [col][k])
#pragma unroll
    for (int i = 0; i < 4; ++i) {
      int lin = t + i * 256;                    // 0..1023
      int col = lin >> 3, seg = lin & 7;
      short8 s = *(const short8*)&Wt[(size_t)col * F_IN + kc + seg * 8];
      *(short8*)&Ws[col * XP + seg * 8] = s;
    }
    __syncthreads();

#pragma unroll
    for (int ks = 0; ks < 2; ++ks) {
      short8 af[4], bf[4];
#pragma unroll
      for (int rt = 0; rt < 4; ++rt)
        af[rt] = *(const short8*)&Xs[(rowbase + rt * 16 + mrow) * XP + ks * 32 + quad * 8];
#pragma unroll
      for (int ct = 0; ct < 4; ++ct)
        bf[ct] = *(const short8*)&Ws[(colbase + ct * 16 + mrow) * XP + ks * 32 + quad * 8];
#pragma unroll
      for (int rt = 0; rt < 4; ++rt)
#pragma unroll
        for (int ct = 0; ct < 4; ++ct)
          acc[rt][ct] = __builtin_amdgcn_mfma_f32_16x16x32_bf16(
              af[rt], bf[ct], acc[rt][ct], 0, 0, 0);
    }
  }

  // epilogue: bias + relu, fp32 store. C layout: row=quad*4+reg, col=mrow
#pragma unroll
  for (int ct = 0; ct < 4; ++ct) {
    int col = colbase + ct * 16 + mrow;
    float bias = b1[col];
#pragma unroll
    for (int rt = 0; rt < 4; ++rt) {
#pragma unroll
      for (int r = 0; r < 4; ++r) {
        int gn = node0 + rowbase + rt * 16 + quad * 4 + r;
        if (gn < n)
          H1[(size_t)gn * D_EMB + col] = fmaxf(acc[rt][ct][r] + bias, 0.f);
      }
    }
  }
}

// -------- mm: Out[n,64] = f(In[n,K]) @ W[K,64] ------------------------------
template<int K, bool PRE>
__global__ __launch_bounds__(256) void mm_kernel(
    const float* __restrict__ In, const int* __restrict__ deg,
    const float* __restrict__ bin, const float* __restrict__ W,
    float* __restrict__ Out, int n)
{
  __shared__ float Hs[64][K + 4];
  __shared__ float Ws[K][64];
  const int t = threadIdx.x;
  const int node0 = blockIdx.x * 64;
  constexpr int KQ = K / 4;

#pragma unroll
  for (int i = 0; i < (64 * KQ) / 256; ++i) {
    int lin = t + i * 256;
    int node = lin / KQ, kq = lin % KQ;
    int gn = node0 + node;
    float4 v = make_float4(0.f, 0.f, 0.f, 0.f);
    if (gn < n) {
      v = *(const float4*)&In[(size_t)gn * K + kq * 4];
      if (PRE) {
        float rd = 1.f / fmaxf((float)deg[gn], 1.f);
        v.x = fmaxf(v.x * rd + bin[kq * 4 + 0], 0.f);
        v.y = fmaxf(v.y * rd + bin[kq * 4 + 1], 0.f);
        v.z = fmaxf(v.z * rd + bin[kq * 4 + 2], 0.f);
        v.w = fmaxf(v.w * rd + bin[kq * 4 + 3], 0.f);
      }
    }
    *(float4*)&Hs[node][kq * 4] = v;
  }
#pragma unroll
  for (int i = 0; i < (K * 64) / 1024; ++i) {
    int lin = t + i * 256;
    ((float4*)&Ws[0][0])[lin] = ((const float4*)W)[lin];
  }
  __syncthreads();

  const int rg = t >> 4, cg = t & 15;
  float acc[4][4];
#pragma unroll
  for (int i = 0; i < 4; ++i)
#pragma unroll
    for (int j = 0; j < 4; ++j) acc[i][j] = 0.f;

#pragma unroll 8
  for (int k = 0; k < K; ++k) {
    float a[4] = {Hs[rg*4+0][k], Hs[rg*4+1][k], Hs[rg*4+2][k], Hs[rg*4+3][k]};
    float4 b = *(const float4*)&Ws[k][cg * 4];
#pragma unroll
    for (int i = 0; i < 4; ++i) {
      acc[i][0] += a[i]*b.x; acc[i][1] += a[i]*b.y;
      acc[i][2] += a[i]*b.z; acc[i][3] += a[i]*b.w;
    }
  }
#pragma unroll
  for (int i = 0; i < 4; ++i) {
    int gn = node0 + rg * 4 + i;
    if (gn < n) {
      float4 o = make_float4(acc[i][0], acc[i][1], acc[i][2], acc[i][3]);
      *(float4*)&Out[(size_t)gn * 64 + cg * 4] = o;
    }
  }
}

// ---------------- CSR build: count, scan, fill ------------------------------
__global__ __launch_bounds__(256) void count_kernel(
    const int* __restrict__ dst, int* __restrict__ cnt, int nE)
{
  int e = blockIdx.x * 256 + threadIdx.x;
  if (e < nE) atomicAdd(&cnt[dst[e]], 1);
}

__global__ __launch_bounds__(256) void scan1_kernel(
    const int* __restrict__ cnt, int* __restrict__ offs,
    int* __restrict__ bsum, int n)
{
  __shared__ int sh[256];
  int t = threadIdx.x;
  int node = blockIdx.x * 256 + t;
  int c = (node < n) ? cnt[node] : 0;
  sh[t] = c;
  __syncthreads();
#pragma unroll
  for (int off = 1; off < 256; off <<= 1) {
    int v = 0;
    if (t >= off) v = sh[t - off];
    __syncthreads();
    if (t >= off) sh[t] += v;
    __syncthreads();
  }
  if (node < n) offs[node] = sh[t] - c;
  if (t == 255) bsum[blockIdx.x] = sh[255];
}

__global__ void scan2_kernel(int* __restrict__ bsum, int nb)
{
  int run = 0;
  for (int i = 0; i < nb; ++i) { int v = bsum[i]; bsum[i] = run; run += v; }
  bsum[nb] = run;
}

__global__ __launch_bounds__(256) void scan3_kernel(
    int* __restrict__ offs, int* __restrict__ cursor,
    const int* __restrict__ bsum, int n, int nb)
{
  int i = blockIdx.x * 256 + threadIdx.x;
  if (i < n) {
    int v = offs[i] + bsum[i >> 8];
    offs[i] = v;
    cursor[i] = v;
  } else if (i == n) {
    offs[n] = bsum[nb];
  }
}

__global__ __launch_bounds__(256) void fill_kernel(
    const int* __restrict__ src, const int* __restrict__ dst,
    int* __restrict__ cursor, int* __restrict__ adj, int nE)
{
  int e = blockIdx.x * 256 + threadIdx.x;
  if (e < nE) {
    int slot = atomicAdd(&cursor[dst[e]], 1);
    adj[slot] = src[e];
  }
}

// ---------------- gather: A[d] = sum_{s in adj[d]} P[s]  (wave per node) ----
__global__ __launch_bounds__(256) void gather_kernel(
    const float* __restrict__ P, const int* __restrict__ offs,
    const int* __restrict__ adj, float* __restrict__ A, int n)
{
  int node = (blockIdx.x * 256 + threadIdx.x) >> 6;
  int lane = threadIdx.x & 63;
  if (node >= n) return;
  int beg = offs[node], end = offs[node + 1];
  float acc0 = 0.f, acc1 = 0.f;
  int j = beg;
  while (j < end) {
    int m = min(end - j, 64);
    int idx = (lane < m) ? adj[j + lane] : 0;
    int q = 0;
    for (; q + 1 < m; q += 2) {
      int s0 = __shfl(idx, q, 64);
      int s1 = __shfl(idx, q + 1, 64);
      acc0 += P[(size_t)s0 * 64 + lane];
      acc1 += P[(size_t)s1 * 64 + lane];
    }
    if (q < m) {
      int s0 = __shfl(idx, q, 64);
      acc0 += P[(size_t)s0 * 64 + lane];
    }
    j += m;
  }
  A[(size_t)node * 64 + lane] = acc0 + acc1;
}

// ---- conv3 epilogue: H4 = relu(A/deg + bc3); accumulate sum/sumsq ----------
__global__ __launch_bounds__(256) void post3_kernel(
    const float* __restrict__ A, const int* __restrict__ deg,
    const float* __restrict__ bc3, float* __restrict__ H4,
    float* __restrict__ stats, int n)
{
  int t = threadIdx.x;
  int f = t & 63, q = t >> 6;
  float b = bc3[f];
  float s = 0.f, s2 = 0.f;
  for (int node = blockIdx.x * 4 + q; node < n; node += gridDim.x * 4) {
    float v = fmaxf(A[(size_t)node * 64 + f] / fmaxf((float)deg[node], 1.f) + b, 0.f);
    H4[(size_t)node * 64 + f] = v;
    s += v; s2 += v * v;
  }
  __shared__ float red[2][4][64];
  red[0][q][f] = s; red[1][q][f] = s2;
  __syncthreads();
  if (t < 128) {
    int which = t >> 6, ff = t & 63;
    float a = red[which][0][ff] + red[which][1][ff] +
              red[which][2][ff] + red[which][3][ff];
    atomicAdd(&stats[which * 64 + ff], a);
  }
}

// ---- fold batchnorm into W2 ------------------------------------------------
__global__ __launch_bounds__(256) void fold_kernel(
    const float* __restrict__ stats, const float* __restrict__ gamma,
    const float* __restrict__ beta, const float* __restrict__ W2,
    const float* __restrict__ b2, float* __restrict__ W2f,
    float* __restrict__ b2f, int n)
{
  __shared__ float rsg[64], corr[64];
  int t = threadIdx.x;
  if (t < 64) {
    float m = stats[t] / (float)n;
    float var = stats[64 + t] / (float)n - m * m;
    float rs = rsqrtf(var + 1e-5f);
    float g = gamma[t] * rs;
    rsg[t] = g;
    corr[t] = beta[t] - m * g;
  }
  __syncthreads();
#pragma unroll
  for (int i = 0; i < 8; ++i) {
    int lin = t + i * 256;
    int k = lin >> 5;
    W2f[lin] = rsg[k] * W2[lin];
  }
  if (t < 32) {
    float a = b2[t];
    for (int k = 0; k < 64; ++k) a += corr[k] * W2[k * 32 + t];
    b2f[t] = a;
  }
}

// ---- final: out = relu(H4 @ W2f + b2f) @ W3 + b3 ---------------------------
__global__ __launch_bounds__(256) void final_kernel(
    const float* __restrict__ H4, const float* __restrict__ W2f,
    const float* __restrict__ b2f, const float* __restrict__ W3,
    const float* __restrict__ b3, float* __restrict__ Out, int n)
{
  __shared__ float Hs[64][68];
  __shared__ float W2s[64][32];
  __shared__ float W3s[32][32];
  __shared__ float Us[64][36];
  __shared__ float b2s[32], b3s[32];
  const int t = threadIdx.x;
  const int node0 = blockIdx.x * 64;

#pragma unroll
  for (int i = 0; i < 4; ++i) {
    int lin = t + i * 256;
    int node = lin >> 4, kq = lin & 15;
    float4 v = make_float4(0.f, 0.f, 0.f, 0.f);
    if (node0 + node < n)
      v = *(const float4*)&H4[(size_t)(node0 + node) * 64 + kq * 4];
    *(float4*)&Hs[node][kq * 4] = v;
  }
#pragma unroll
  for (int i = 0; i < 2; ++i) {
    int lin = t + i * 256;
    ((float4*)&W2s[0][0])[lin] = ((const float4*)W2f)[lin];
  }
  ((float4*)&W3s[0][0])[t & 255] = ((const float4*)W3)[t & 255];
  if (t < 32) { b2s[t] = b2f[t]; b3s[t] = b3[t]; }
  __syncthreads();

  const int rg = t >> 4, cg = t & 15;
  float acc[4][2] = {{0.f,0.f},{0.f,0.f},{0.f,0.f},{0.f,0.f}};
#pragma unroll 8
  for (int k = 0; k < 64; ++k) {
    float a[4] = {Hs[rg*4+0][k], Hs[rg*4+1][k], Hs[rg*4+2][k], Hs[rg*4+3][k]};
    float w0 = W2s[k][cg*2], w1 = W2s[k][cg*2+1];
#pragma unroll
    for (int i = 0; i < 4; ++i) { acc[i][0] += a[i]*w0; acc[i][1] += a[i]*w1; }
  }
#pragma unroll
  for (int i = 0; i < 4; ++i) {
    Us[rg*4+i][cg*2+0] = fmaxf(acc[i][0] + b2s[cg*2+0], 0.f);
    Us[rg*4+i][cg*2+1] = fmaxf(acc[i][1] + b2s[cg*2+1], 0.f);
  }
  __syncthreads();

  float acc2[4][2] = {{0.f,0.f},{0.f,0.f},{0.f,0.f},{0.f,0.f}};
#pragma unroll
  for (int k = 0; k < 32; ++k) {
    float a[4] = {Us[rg*4+0][k], Us[rg*4+1][k], Us[rg*4+2][k], Us[rg*4+3][k]};
    float w0 = W3s[k][cg*2], w1 = W3s[k][cg*2+1];
#pragma unroll
    for (int i = 0; i < 4; ++i) { acc2[i][0] += a[i]*w0; acc2[i][1] += a[i]*w1; }
  }
  float (*Os)[36] = (float(*)[36])Hs;
#pragma unroll
  for (int i = 0; i < 4; ++i) {
    Os[rg*4+i][cg*2+0] = acc2[i][0] + b3s[cg*2+0];
    Os[rg*4+i][cg*2+1] = acc2[i][1] + b3s[cg*2+1];
  }
  __syncthreads();
#pragma unroll
  for (int i = 0; i < 2; ++i) {
    int lin = t + i * 256;
    int node = lin >> 3, c4 = lin & 7;
    if (node0 + node < n)
      *(float4*)&Out[(size_t)(node0 + node) * 32 + c4 * 4] =
          *(float4*)&Os[node][c4 * 4];
  }
}

// ---------------------------------------------------------------------------
extern "C" void kernel_launch(void* const* d_in, const int* in_sizes, int n_in,
                              void* d_out, int out_size, void* d_ws, size_t ws_size,
                              hipStream_t stream)
{
  const float* X     = (const float*)d_in[0];
  const float* W1    = (const float*)d_in[1];
  const float* b1    = (const float*)d_in[2];
  const float* Wc1   = (const float*)d_in[3];
  const float* bc1   = (const float*)d_in[4];
  const float* Wc2   = (const float*)d_in[5];
  const float* bc2   = (const float*)d_in[6];
  const float* Wc3   = (const float*)d_in[7];
  const float* bc3   = (const float*)d_in[8];
  const float* gamma = (const float*)d_in[9];
  const float* beta  = (const float*)d_in[10];
  const float* W2    = (const float*)d_in[11];
  const float* b2    = (const float*)d_in[12];
  const float* W3    = (const float*)d_in[13];
  const float* b3    = (const float*)d_in[14];
  const int*   ei    = (const int*)d_in[15];

  const int n  = in_sizes[0] / F_IN;
  const int nE = in_sizes[15] / 2;
  const int* src  = ei;
  const int* dstv = ei + nE;

  float* ws    = (float*)d_ws;
  float* H1    = ws;                                   // n*128 (H4 reuses)
  float* P     = H1 + (size_t)n * D_EMB;               // n*64
  float* A     = P  + (size_t)n * D_HID;               // n*64
  float* stats = A  + (size_t)n * D_HID;               // 128
  float* W2f   = stats + 128;                          // 2048
  float* b2f   = W2f + 2048;                           // 32
  int*   cnt    = (int*)(b2f + 32);                    // n
  int*   offs   = cnt + n;                             // n+1
  int*   cursor = offs + n + 1;                        // n
  int*   bsum   = cursor + n;                          // 512
  int*   adj    = bsum + 512;                          // nE
  unsigned short* Wt = (unsigned short*)(adj + nE);    // 128*512 bf16
  float* H4    = H1;                                   // reuse H1

  const int nb  = (n + 63) / 64;
  const int nb2 = (n + 255) / 256;
  const int eb  = (nE + 255) / 256;
  const int gatherBlocks = (int)(((long long)n * 64 + 255) / 256);

  hipMemsetAsync(cnt,   0, (size_t)n * sizeof(int), stream);
  hipMemsetAsync(stats, 0, 128 * sizeof(float), stream);

  // W1 -> bf16 transposed, then bf16-MFMA lin1
  wt_kernel<<<(D_EMB * F_IN) / 256, 256, 0, stream>>>(W1, Wt);
  lin1_mfma_kernel<<<(n + 127) / 128, 256, 0, stream>>>(X, Wt, b1, H1, n);

  // CSR build
  count_kernel<<<eb, 256, 0, stream>>>(dstv, cnt, nE);
  scan1_kernel<<<nb2, 256, 0, stream>>>(cnt, offs, bsum, n);
  scan2_kernel<<<1, 1, 0, stream>>>(bsum, nb2);
  scan3_kernel<<<(n + 256) / 256, 256, 0, stream>>>(offs, cursor, bsum, n, nb2);
  fill_kernel<<<eb, 256, 0, stream>>>(src, dstv, cursor, adj, nE);

  // conv1: P = H1 @ Wc1 ; A = gather-sum(P)
  mm_kernel<128, false><<<nb, 256, 0, stream>>>(H1, nullptr, nullptr, Wc1, P, n);
  gather_kernel<<<gatherBlocks, 256, 0, stream>>>(P, offs, adj, A, n);

  // conv2
  mm_kernel<64, true><<<nb, 256, 0, stream>>>(A, cnt, bc1, Wc2, P, n);
  gather_kernel<<<gatherBlocks, 256, 0, stream>>>(P, offs, adj, A, n);

  // conv3
  mm_kernel<64, true><<<nb, 256, 0, stream>>>(A, cnt, bc2, Wc3, P, n);
  gather_kernel<<<gatherBlocks, 256, 0, stream>>>(P, offs, adj, A, n);

  // conv3 epilogue + batch stats
  post3_kernel<<<256, 256, 0, stream>>>(A, cnt, bc3, H4, stats, n);

  // fold batchnorm into W2, then fused lin2+lin3
  fold_kernel<<<1, 256, 0, stream>>>(stats, gamma, beta, W2, b2, W2f, b2f, n);
  final_kernel<<<nb, 256, 0, stream>>>(H4, W2f, b2f, W3, b3, (float*)d_out, n);
}

// Round 4
// 889.911 us; speedup vs baseline: 1.9531x; 1.0290x over previous
//
#include <hip/hip_runtime.h>
#include <cstdint>
#include <cstddef>

constexpr int F_IN  = 512;
constexpr int D_EMB = 128;
constexpr int D_HID = 64;
constexpr int N_CLS = 32;

typedef __attribute__((ext_vector_type(8))) short short8;
typedef __attribute__((ext_vector_type(4))) float floatx4;

__device__ inline unsigned short f2bf(float f) {
  union { float f; uint32_t u; } v; v.f = f;
  uint32_t r = v.u + 0x7FFF + ((v.u >> 16) & 1);   // round-to-nearest-even
  return (unsigned short)(r >> 16);
}

// ---- W1 -> fragment-linear bf16: Wt2[kc8][ct][ks][lane] of short8 ----------
// frag element: col = ct*16 + (lane&15), k = kc8*64 + ks*32 + (lane>>4)*8 + j
__global__ __launch_bounds__(256) void wt_kernel(
    const float* __restrict__ W1, short8* __restrict__ Wt2)
{
  int idx = blockIdx.x * 256 + threadIdx.x;     // 0..8191
  int kc8 = idx >> 10, lin = idx & 1023;
  int ct = lin >> 7, rem = lin & 127, ks = rem >> 6, ln = rem & 63;
  int col = ct * 16 + (ln & 15);
  int k0 = kc8 * 64 + ks * 32 + (ln >> 4) * 8;
  short8 s;
#pragma unroll
  for (int j = 0; j < 8; ++j)
    s[j] = (short)f2bf(W1[(size_t)(k0 + j) * D_EMB + col]);
  Wt2[idx] = s;
}

// ---- lin1 MFMA: H1 = relu(X @ W1 + b1) -------------------------------------
// block: 128 rows x 128 cols, 4 waves (2x2). W via frag-linear LDS (16KB),
// X direct global->register with in-register bf16 conversion.
__global__ __launch_bounds__(256) void lin1_mfma_kernel(
    const float* __restrict__ X, const short8* __restrict__ Wt2,
    const float* __restrict__ b1, float* __restrict__ H1, int n)
{
  __shared__ short8 Ws[1024];                   // [ct(8)][ks(2)][lane(64)]

  const int t = threadIdx.x;
  const int wave = t >> 6, lane = t & 63;
  const int quad = lane >> 4, mrow = lane & 15;
  const int node0 = blockIdx.x * 128;
  const int rowbase = node0 + (wave >> 1) * 64;
  const int cw = (wave & 1) * 4;                // this wave's first col-tile

  // per-rt row pointers (clamped; garbage rows masked at store)
  const float* rowp[4];
#pragma unroll
  for (int rt = 0; rt < 4; ++rt) {
    int r = rowbase + rt * 16 + mrow;
    if (r >= n) r = n - 1;
    rowp[rt] = &X[(size_t)r * F_IN + quad * 8];
  }

  floatx4 acc[4][4];
#pragma unroll
  for (int i = 0; i < 4; ++i)
#pragma unroll
    for (int j = 0; j < 4; ++j) acc[i][j] = (floatx4){0.f, 0.f, 0.f, 0.f};

  for (int kc8 = 0; kc8 < 8; ++kc8) {
    __syncthreads();
#pragma unroll
    for (int i = 0; i < 4; ++i) {
      int lin = t + i * 256;
      Ws[lin] = Wt2[kc8 * 1024 + lin];          // coalesced, conflict-free
    }
    __syncthreads();

#pragma unroll
    for (int ks = 0; ks < 2; ++ks) {
      float4 xv[4][2];
#pragma unroll
      for (int rt = 0; rt < 4; ++rt) {
        const float* p = rowp[rt] + kc8 * 64 + ks * 32;
        xv[rt][0] = *(const float4*)p;
        xv[rt][1] = *(const float4*)(p + 4);
      }
      short8 bf[4];
#pragma unroll
      for (int c = 0; c < 4; ++c)
        bf[c] = Ws[((cw + c) * 2 + ks) * 64 + lane];
#pragma unroll
      for (int rt = 0; rt < 4; ++rt) {
        short8 af;
        af[0] = (short)f2bf(xv[rt][0].x); af[1] = (short)f2bf(xv[rt][0].y);
        af[2] = (short)f2bf(xv[rt][0].z); af[3] = (short)f2bf(xv[rt][0].w);
        af[4] = (short)f2bf(xv[rt][1].x); af[5] = (short)f2bf(xv[rt][1].y);
        af[6] = (short)f2bf(xv[rt][1].z); af[7] = (short)f2bf(xv[rt][1].w);
#pragma unroll
        for (int c = 0; c < 4; ++c)
          acc[rt][c] = __builtin_amdgcn_mfma_f32_16x16x32_bf16(
              af, bf[c], acc[rt][c], 0, 0, 0);
      }
    }
  }

  // epilogue: bias + relu. C layout: row=quad*4+reg, col=lane&15
#pragma unroll
  for (int ct = 0; ct < 4; ++ct) {
    int col = (cw + ct) * 16 + mrow;
    float bias = b1[col];
#pragma unroll
    for (int rt = 0; rt < 4; ++rt) {
#pragma unroll
      for (int r = 0; r < 4; ++r) {
        int gn = rowbase + rt * 16 + quad * 4 + r;
        if (gn < n)
          H1[(size_t)gn * D_EMB + col] = fmaxf(acc[rt][ct][r] + bias, 0.f);
      }
    }
  }
}

// -------- mm: Out[n,64] = f(In[n,K]) @ W[K,64] ------------------------------
template<int K, bool PRE>
__global__ __launch_bounds__(256) void mm_kernel(
    const float* __restrict__ In, const int* __restrict__ deg,
    const float* __restrict__ bin, const float* __restrict__ W,
    float* __restrict__ Out, int n)
{
  __shared__ float Hs[64][K + 4];
  __shared__ float Ws[K][64];
  const int t = threadIdx.x;
  const int node0 = blockIdx.x * 64;
  constexpr int KQ = K / 4;

#pragma unroll
  for (int i = 0; i < (64 * KQ) / 256; ++i) {
    int lin = t + i * 256;
    int node = lin / KQ, kq = lin % KQ;
    int gn = node0 + node;
    float4 v = make_float4(0.f, 0.f, 0.f, 0.f);
    if (gn < n) {
      v = *(const float4*)&In[(size_t)gn * K + kq * 4];
      if (PRE) {
        float rd = 1.f / fmaxf((float)deg[gn], 1.f);
        v.x = fmaxf(v.x * rd + bin[kq * 4 + 0], 0.f);
        v.y = fmaxf(v.y * rd + bin[kq * 4 + 1], 0.f);
        v.z = fmaxf(v.z * rd + bin[kq * 4 + 2], 0.f);
        v.w = fmaxf(v.w * rd + bin[kq * 4 + 3], 0.f);
      }
    }
    *(float4*)&Hs[node][kq * 4] = v;
  }
#pragma unroll
  for (int i = 0; i < (K * 64) / 1024; ++i) {
    int lin = t + i * 256;
    ((float4*)&Ws[0][0])[lin] = ((const float4*)W)[lin];
  }
  __syncthreads();

  const int rg = t >> 4, cg = t & 15;
  float acc[4][4];
#pragma unroll
  for (int i = 0; i < 4; ++i)
#pragma unroll
    for (int j = 0; j < 4; ++j) acc[i][j] = 0.f;

#pragma unroll 8
  for (int k = 0; k < K; ++k) {
    float a[4] = {Hs[rg*4+0][k], Hs[rg*4+1][k], Hs[rg*4+2][k], Hs[rg*4+3][k]};
    float4 b = *(const float4*)&Ws[k][cg * 4];
#pragma unroll
    for (int i = 0; i < 4; ++i) {
      acc[i][0] += a[i]*b.x; acc[i][1] += a[i]*b.y;
      acc[i][2] += a[i]*b.z; acc[i][3] += a[i]*b.w;
    }
  }
#pragma unroll
  for (int i = 0; i < 4; ++i) {
    int gn = node0 + rg * 4 + i;
    if (gn < n) {
      float4 o = make_float4(acc[i][0], acc[i][1], acc[i][2], acc[i][3]);
      *(float4*)&Out[(size_t)gn * 64 + cg * 4] = o;
    }
  }
}

// ---------------- CSR build: count, scan, fill ------------------------------
__global__ __launch_bounds__(256) void count_kernel(
    const int* __restrict__ dst, int* __restrict__ cnt, int nE)
{
  int e = blockIdx.x * 256 + threadIdx.x;
  if (e < nE) atomicAdd(&cnt[dst[e]], 1);
}

__global__ __launch_bounds__(256) void scan1_kernel(
    const int* __restrict__ cnt, int* __restrict__ offs,
    int* __restrict__ bsum, int n)
{
  __shared__ int sh[256];
  int t = threadIdx.x;
  int node = blockIdx.x * 256 + t;
  int c = (node < n) ? cnt[node] : 0;
  sh[t] = c;
  __syncthreads();
#pragma unroll
  for (int off = 1; off < 256; off <<= 1) {
    int v = 0;
    if (t >= off) v = sh[t - off];
    __syncthreads();
    if (t >= off) sh[t] += v;
    __syncthreads();
  }
  if (node < n) offs[node] = sh[t] - c;
  if (t == 255) bsum[blockIdx.x] = sh[255];
}

// parallel exclusive scan of nb block sums (single block, chunked)
__global__ __launch_bounds__(256) void scan2_kernel(int* __restrict__ bsum, int nb)
{
  __shared__ int sh[256];
  __shared__ int carry;
  int t = threadIdx.x;
  if (t == 0) carry = 0;
  __syncthreads();
  for (int base = 0; base < nb; base += 256) {
    int i = base + t;
    int v = (i < nb) ? bsum[i] : 0;
    sh[t] = v;
    __syncthreads();
#pragma unroll
    for (int off = 1; off < 256; off <<= 1) {
      int u = 0;
      if (t >= off) u = sh[t - off];
      __syncthreads();
      if (t >= off) sh[t] += u;
      __syncthreads();
    }
    int c0 = carry;
    int incl = sh[t], total = sh[255];
    if (i < nb) bsum[i] = c0 + incl - v;      // exclusive
    __syncthreads();
    if (t == 0) carry = c0 + total;
    __syncthreads();
  }
  if (t == 0) bsum[nb] = carry;
}

__global__ __launch_bounds__(256) void scan3_kernel(
    int* __restrict__ offs, int* __restrict__ cursor,
    const int* __restrict__ bsum, int n, int nb)
{
  int i = blockIdx.x * 256 + threadIdx.x;
  if (i < n) {
    int v = offs[i] + bsum[i >> 8];
    offs[i] = v;
    cursor[i] = v;
  } else if (i == n) {
    offs[n] = bsum[nb];
  }
}

__global__ __launch_bounds__(256) void fill_kernel(
    const int* __restrict__ src, const int* __restrict__ dst,
    int* __restrict__ cursor, int* __restrict__ adj, int nE)
{
  int e = blockIdx.x * 256 + threadIdx.x;
  if (e < nE) {
    int slot = atomicAdd(&cursor[dst[e]], 1);
    // atomicExch instead of plain store: atomics write exactly their payload
    // (no 64B line write-through for random scatter — R3 showed 16x write amp)
    atomicExch(&adj[slot], src[e]);
  }
}

// ---------------- gather: A[d] = sum_{s in adj[d]} P[s]  (wave per node) ----
__global__ __launch_bounds__(256) void gather_kernel(
    const float* __restrict__ P, const int* __restrict__ offs,
    const int* __restrict__ adj, float* __restrict__ A, int n)
{
  int node = (blockIdx.x * 256 + threadIdx.x) >> 6;
  int lane = threadIdx.x & 63;
  if (node >= n) return;
  int beg = offs[node], end = offs[node + 1];
  float acc0 = 0.f, acc1 = 0.f;
  int j = beg;
  while (j < end) {
    int m = min(end - j, 64);
    int idx = (lane < m) ? adj[j + lane] : 0;
    int q = 0;
    for (; q + 1 < m; q += 2) {
      int s0 = __shfl(idx, q, 64);
      int s1 = __shfl(idx, q + 1, 64);
      acc0 += P[(size_t)s0 * 64 + lane];
      acc1 += P[(size_t)s1 * 64 + lane];
    }
    if (q < m) {
      int s0 = __shfl(idx, q, 64);
      acc0 += P[(size_t)s0 * 64 + lane];
    }
    j += m;
  }
  A[(size_t)node * 64 + lane] = acc0 + acc1;
}

// ---- conv3 epilogue: H4 = relu(A/deg + bc3); accumulate sum/sumsq ----------
__global__ __launch_bounds__(256) void post3_kernel(
    const float* __restrict__ A, const int* __restrict__ deg,
    const float* __restrict__ bc3, float* __restrict__ H4,
    float* __restrict__ stats, int n)
{
  int t = threadIdx.x;
  int f = t & 63, q = t >> 6;
  float b = bc3[f];
  float s = 0.f, s2 = 0.f;
  for (int node = blockIdx.x * 4 + q; node < n; node += gridDim.x * 4) {
    float v = fmaxf(A[(size_t)node * 64 + f] / fmaxf((float)deg[node], 1.f) + b, 0.f);
    H4[(size_t)node * 64 + f] = v;
    s += v; s2 += v * v;
  }
  __shared__ float red[2][4][64];
  red[0][q][f] = s; red[1][q][f] = s2;
  __syncthreads();
  if (t < 128) {
    int which = t >> 6, ff = t & 63;
    float a = red[which][0][ff] + red[which][1][ff] +
              red[which][2][ff] + red[which][3][ff];
    atomicAdd(&stats[which * 64 + ff], a);
  }
}

// ---- fold batchnorm into W2 ------------------------------------------------
__global__ __launch_bounds__(256) void fold_kernel(
    const float* __restrict__ stats, const float* __restrict__ gamma,
    const float* __restrict__ beta, const float* __restrict__ W2,
    const float* __restrict__ b2, float* __restrict__ W2f,
    float* __restrict__ b2f, int n)
{
  __shared__ float rsg[64], corr[64];
  int t = threadIdx.x;
  if (t < 64) {
    float m = stats[t] / (float)n;
    float var = stats[64 + t] / (float)n - m * m;
    float rs = rsqrtf(var + 1e-5f);
    float g = gamma[t] * rs;
    rsg[t] = g;
    corr[t] = beta[t] - m * g;
  }
  __syncthreads();
#pragma unroll
  for (int i = 0; i < 8; ++i) {
    int lin = t + i * 256;
    int k = lin >> 5;
    W2f[lin] = rsg[k] * W2[lin];
  }
  if (t < 32) {
    float a = b2[t];
    for (int k = 0; k < 64; ++k) a += corr[k] * W2[k * 32 + t];
    b2f[t] = a;
  }
}

// ---- final: out = relu(H4 @ W2f + b2f) @ W3 + b3 ---------------------------
__global__ __launch_bounds__(256) void final_kernel(
    const float* __restrict__ H4, const float* __restrict__ W2f,
    const float* __restrict__ b2f, const float* __restrict__ W3,
    const float* __restrict__ b3, float* __restrict__ Out, int n)
{
  __shared__ float Hs[64][68];
  __shared__ float W2s[64][32];
  __shared__ float W3s[32][32];
  __shared__ float Us[64][36];
  __shared__ float b2s[32], b3s[32];
  const int t = threadIdx.x;
  const int node0 = blockIdx.x * 64;

#pragma unroll
  for (int i = 0; i < 4; ++i) {
    int lin = t + i * 256;
    int node = lin >> 4, kq = lin & 15;
    float4 v = make_float4(0.f, 0.f, 0.f, 0.f);
    if (node0 + node < n)
      v = *(const float4*)&H4[(size_t)(node0 + node) * 64 + kq * 4];
    *(float4*)&Hs[node][kq * 4] = v;
  }
#pragma unroll
  for (int i = 0; i < 2; ++i) {
    int lin = t + i * 256;
    ((float4*)&W2s[0][0])[lin] = ((const float4*)W2f)[lin];
  }
  ((float4*)&W3s[0][0])[t & 255] = ((const float4*)W3)[t & 255];
  if (t < 32) { b2s[t] = b2f[t]; b3s[t] = b3[t]; }
  __syncthreads();

  const int rg = t >> 4, cg = t & 15;
  float acc[4][2] = {{0.f,0.f},{0.f,0.f},{0.f,0.f},{0.f,0.f}};
#pragma unroll 8
  for (int k = 0; k < 64; ++k) {
    float a[4] = {Hs[rg*4+0][k], Hs[rg*4+1][k], Hs[rg*4+2][k], Hs[rg*4+3][k]};
    float w0 = W2s[k][cg*2], w1 = W2s[k][cg*2+1];
#pragma unroll
    for (int i = 0; i < 4; ++i) { acc[i][0] += a[i]*w0; acc[i][1] += a[i]*w1; }
  }
#pragma unroll
  for (int i = 0; i < 4; ++i) {
    Us[rg*4+i][cg*2+0] = fmaxf(acc[i][0] + b2s[cg*2+0], 0.f);
    Us[rg*4+i][cg*2+1] = fmaxf(acc[i][1] + b2s[cg*2+1], 0.f);
  }
  __syncthreads();

  float acc2[4][2] = {{0.f,0.f},{0.f,0.f},{0.f,0.f},{0.f,0.f}};
#pragma unroll
  for (int k = 0; k < 32; ++k) {
    float a[4] = {Us[rg*4+0][k], Us[rg*4+1][k], Us[rg*4+2][k], Us[rg*4+3][k]};
    float w0 = W3s[k][cg*2], w1 = W3s[k][cg*2+1];
#pragma unroll
    for (int i = 0; i < 4; ++i) { acc2[i][0] += a[i]*w0; acc2[i][1] += a[i]*w1; }
  }
  float (*Os)[36] = (float(*)[36])Hs;
#pragma unroll
  for (int i = 0; i < 4; ++i) {
    Os[rg*4+i][cg*2+0] = acc2[i][0] + b3s[cg*2+0];
    Os[rg*4+i][cg*2+1] = acc2[i][1] + b3s[cg*2+1];
  }
  __syncthreads();
#pragma unroll
  for (int i = 0; i < 2; ++i) {
    int lin = t + i * 256;
    int node = lin >> 3, c4 = lin & 7;
    if (node0 + node < n)
      *(float4*)&Out[(size_t)(node0 + node) * 32 + c4 * 4] =
          *(float4*)&Os[node][c4 * 4];
  }
}

// ---------------------------------------------------------------------------
extern "C" void kernel_launch(void* const* d_in, const int* in_sizes, int n_in,
                              void* d_out, int out_size, void* d_ws, size_t ws_size,
                              hipStream_t stream)
{
  const float* X     = (const float*)d_in[0];
  const float* W1    = (const float*)d_in[1];
  const float* b1    = (const float*)d_in[2];
  const float* Wc1   = (const float*)d_in[3];
  const float* bc1   = (const float*)d_in[4];
  const float* Wc2   = (const float*)d_in[5];
  const float* bc2   = (const float*)d_in[6];
  const float* Wc3   = (const float*)d_in[7];
  const float* bc3   = (const float*)d_in[8];
  const float* gamma = (const float*)d_in[9];
  const float* beta  = (const float*)d_in[10];
  const float* W2    = (const float*)d_in[11];
  const float* b2    = (const float*)d_in[12];
  const float* W3    = (const float*)d_in[13];
  const float* b3    = (const float*)d_in[14];
  const int*   ei    = (const int*)d_in[15];

  const int n  = in_sizes[0] / F_IN;
  const int nE = in_sizes[15] / 2;
  const int* src  = ei;
  const int* dstv = ei + nE;

  float* ws    = (float*)d_ws;
  float* H1    = ws;                                   // n*128 (H4 reuses)
  float* P     = H1 + (size_t)n * D_EMB;               // n*64
  float* A     = P  + (size_t)n * D_HID;               // n*64
  float* stats = A  + (size_t)n * D_HID;               // 128
  float* W2f   = stats + 128;                          // 2048
  float* b2f   = W2f + 2048;                           // 32
  int*   cnt    = (int*)(b2f + 32);                    // n
  int*   offs   = cnt + n;                             // n+1
  int*   cursor = offs + n + 1;                        // n
  int*   bsum   = cursor + n;                          // 512
  int*   adj    = bsum + 512;                          // nE
  short8* Wt2  = (short8*)(adj + nE);                  // 8192 short8 = 128KB
  float* H4    = H1;                                   // reuse H1

  const int nb  = (n + 63) / 64;
  const int nb2 = (n + 255) / 256;
  const int eb  = (nE + 255) / 256;
  const int gatherBlocks = (int)(((long long)n * 64 + 255) / 256);

  hipMemsetAsync(cnt,   0, (size_t)n * sizeof(int), stream);
  hipMemsetAsync(stats, 0, 128 * sizeof(float), stream);

  // W1 -> fragment-linear bf16, then bf16-MFMA lin1
  wt_kernel<<<32, 256, 0, stream>>>(W1, Wt2);
  lin1_mfma_kernel<<<(n + 127) / 128, 256, 0, stream>>>(X, Wt2, b1, H1, n);

  // CSR build
  count_kernel<<<eb, 256, 0, stream>>>(dstv, cnt, nE);
  scan1_kernel<<<nb2, 256, 0, stream>>>(cnt, offs, bsum, n);
  scan2_kernel<<<1, 256, 0, stream>>>(bsum, nb2);
  scan3_kernel<<<(n + 256) / 256, 256, 0, stream>>>(offs, cursor, bsum, n, nb2);
  fill_kernel<<<eb, 256, 0, stream>>>(src, dstv, cursor, adj, nE);

  // conv1: P = H1 @ Wc1 ; A = gather-sum(P)
  mm_kernel<128, false><<<nb, 256, 0, stream>>>(H1, nullptr, nullptr, Wc1, P, n);
  gather_kernel<<<gatherBlocks, 256, 0, stream>>>(P, offs, adj, A, n);

  // conv2
  mm_kernel<64, true><<<nb, 256, 0, stream>>>(A, cnt, bc1, Wc2, P, n);
  gather_kernel<<<gatherBlocks, 256, 0, stream>>>(P, offs, adj, A, n);

  // conv3
  mm_kernel<64, true><<<nb, 256, 0, stream>>>(A, cnt, bc2, Wc3, P, n);
  gather_kernel<<<gatherBlocks, 256, 0, stream>>>(P, offs, adj, A, n);

  // conv3 epilogue + batch stats
  post3_kernel<<<256, 256, 0, stream>>>(A, cnt, bc3, H4, stats, n);

  // fold batchnorm into W2, then fused lin2+lin3
  fold_kernel<<<1, 256, 0, stream>>>(stats, gamma, beta, W2, b2, W2f, b2f, n);
  final_kernel<<<nb, 256, 0, stream>>>(H4, W2f, b2f, W3, b3, (float*)d_out, n);
}

// Round 6
// 743.992 us; speedup vs baseline: 2.3361x; 1.1961x over previous
//
#include <hip/hip_runtime.h>
#include <cstdint>
#include <cstddef>

constexpr int F_IN  = 512;
constexpr int D_EMB = 128;
constexpr int D_HID = 64;
constexpr int N_CLS = 32;

typedef __attribute__((ext_vector_type(8))) short short8;
typedef __attribute__((ext_vector_type(4))) float floatx4;

__device__ inline unsigned short f2bf(float f) {
  union { float f; uint32_t u; } v; v.f = f;
  uint32_t r = v.u + 0x7FFF + ((v.u >> 16) & 1);   // round-to-nearest-even
  return (unsigned short)(r >> 16);
}

// ---- W1 -> fragment-linear bf16: Wt2[kc8][ct][ks][lane] of short8 ----------
__global__ __launch_bounds__(256) void wt_kernel(
    const float* __restrict__ W1, short8* __restrict__ Wt2)
{
  int idx = blockIdx.x * 256 + threadIdx.x;     // 0..8191
  int kc8 = idx >> 10, lin = idx & 1023;
  int ct = lin >> 7, rem = lin & 127, ks = rem >> 6, ln = rem & 63;
  int col = ct * 16 + (ln & 15);
  int k0 = kc8 * 64 + ks * 32 + (ln >> 4) * 8;
  short8 s;
#pragma unroll
  for (int j = 0; j < 8; ++j)
    s[j] = (short)f2bf(W1[(size_t)(k0 + j) * D_EMB + col]);
  Wt2[idx] = s;
}

// ---- lin1 MFMA: H1 = relu(X @ W1 + b1) -------------------------------------
__global__ __launch_bounds__(256) void lin1_mfma_kernel(
    const float* __restrict__ X, const short8* __restrict__ Wt2,
    const float* __restrict__ b1, float* __restrict__ H1, int n)
{
  __shared__ short8 Ws[1024];                   // [ct(8)][ks(2)][lane(64)]

  const int t = threadIdx.x;
  const int wave = t >> 6, lane = t & 63;
  const int quad = lane >> 4, mrow = lane & 15;
  const int node0 = blockIdx.x * 128;
  const int rowbase = node0 + (wave >> 1) * 64;
  const int cw = (wave & 1) * 4;

  const float* rowp[4];
#pragma unroll
  for (int rt = 0; rt < 4; ++rt) {
    int r = rowbase + rt * 16 + mrow;
    if (r >= n) r = n - 1;
    rowp[rt] = &X[(size_t)r * F_IN + quad * 8];
  }

  floatx4 acc[4][4];
#pragma unroll
  for (int i = 0; i < 4; ++i)
#pragma unroll
    for (int j = 0; j < 4; ++j) acc[i][j] = (floatx4){0.f, 0.f, 0.f, 0.f};

  for (int kc8 = 0; kc8 < 8; ++kc8) {
    __syncthreads();
#pragma unroll
    for (int i = 0; i < 4; ++i) {
      int lin = t + i * 256;
      Ws[lin] = Wt2[kc8 * 1024 + lin];
    }
    __syncthreads();

#pragma unroll
    for (int ks = 0; ks < 2; ++ks) {
      float4 xv[4][2];
#pragma unroll
      for (int rt = 0; rt < 4; ++rt) {
        const float* p = rowp[rt] + kc8 * 64 + ks * 32;
        xv[rt][0] = *(const float4*)p;
        xv[rt][1] = *(const float4*)(p + 4);
      }
      short8 bf[4];
#pragma unroll
      for (int c = 0; c < 4; ++c)
        bf[c] = Ws[((cw + c) * 2 + ks) * 64 + lane];
#pragma unroll
      for (int rt = 0; rt < 4; ++rt) {
        short8 af;
        af[0] = (short)f2bf(xv[rt][0].x); af[1] = (short)f2bf(xv[rt][0].y);
        af[2] = (short)f2bf(xv[rt][0].z); af[3] = (short)f2bf(xv[rt][0].w);
        af[4] = (short)f2bf(xv[rt][1].x); af[5] = (short)f2bf(xv[rt][1].y);
        af[6] = (short)f2bf(xv[rt][1].z); af[7] = (short)f2bf(xv[rt][1].w);
#pragma unroll
        for (int c = 0; c < 4; ++c)
          acc[rt][c] = __builtin_amdgcn_mfma_f32_16x16x32_bf16(
              af, bf[c], acc[rt][c], 0, 0, 0);
      }
    }
  }

#pragma unroll
  for (int ct = 0; ct < 4; ++ct) {
    int col = (cw + ct) * 16 + mrow;
    float bias = b1[col];
#pragma unroll
    for (int rt = 0; rt < 4; ++rt) {
#pragma unroll
      for (int r = 0; r < 4; ++r) {
        int gn = rowbase + rt * 16 + quad * 4 + r;
        if (gn < n)
          H1[(size_t)gn * D_EMB + col] = fmaxf(acc[rt][ct][r] + bias, 0.f);
      }
    }
  }
}

// -------- mm: P[n,64](fp32) = f(In[n,K]) @ W[K,64] --------------------------
template<int K, bool PRE>
__global__ __launch_bounds__(256) void mm_kernel(
    const float* __restrict__ In, const int* __restrict__ deg,
    const float* __restrict__ bin, const float* __restrict__ W,
    float* __restrict__ Out, int n)
{
  __shared__ float Hs[64][K + 4];
  __shared__ float Ws[K][64];
  const int t = threadIdx.x;
  const int node0 = blockIdx.x * 64;
  constexpr int KQ = K / 4;

#pragma unroll
  for (int i = 0; i < (64 * KQ) / 256; ++i) {
    int lin = t + i * 256;
    int node = lin / KQ, kq = lin % KQ;
    int gn = node0 + node;
    float4 v = make_float4(0.f, 0.f, 0.f, 0.f);
    if (gn < n) {
      v = *(const float4*)&In[(size_t)gn * K + kq * 4];
      if (PRE) {
        float rd = 1.f / fmaxf((float)deg[gn], 1.f);
        v.x = fmaxf(v.x * rd + bin[kq * 4 + 0], 0.f);
        v.y = fmaxf(v.y * rd + bin[kq * 4 + 1], 0.f);
        v.z = fmaxf(v.z * rd + bin[kq * 4 + 2], 0.f);
        v.w = fmaxf(v.w * rd + bin[kq * 4 + 3], 0.f);
      }
    }
    *(float4*)&Hs[node][kq * 4] = v;
  }
#pragma unroll
  for (int i = 0; i < (K * 64) / 1024; ++i) {
    int lin = t + i * 256;
    ((float4*)&Ws[0][0])[lin] = ((const float4*)W)[lin];
  }
  __syncthreads();

  const int rg = t >> 4, cg = t & 15;
  float acc[4][4];
#pragma unroll
  for (int i = 0; i < 4; ++i)
#pragma unroll
    for (int j = 0; j < 4; ++j) acc[i][j] = 0.f;

#pragma unroll 8
  for (int k = 0; k < K; ++k) {
    float a[4] = {Hs[rg*4+0][k], Hs[rg*4+1][k], Hs[rg*4+2][k], Hs[rg*4+3][k]};
    float4 b = *(const float4*)&Ws[k][cg * 4];
#pragma unroll
    for (int i = 0; i < 4; ++i) {
      acc[i][0] += a[i]*b.x; acc[i][1] += a[i]*b.y;
      acc[i][2] += a[i]*b.z; acc[i][3] += a[i]*b.w;
    }
  }
#pragma unroll
  for (int i = 0; i < 4; ++i) {
    int gn = node0 + rg * 4 + i;
    if (gn < n) {
      float4 o = make_float4(acc[i][0], acc[i][1], acc[i][2], acc[i][3]);
      *(float4*)&Out[(size_t)gn * 64 + cg * 4] = o;
    }
  }
}

// ============== CSR build: bucketed, no global scatter ======================
// bucket = dst >> 9 (512 nodes/bucket); chunk = 8192 edges/block.
// G[b*B + blk] = count of chunk blk's edges in bucket b (bucket-major).

__global__ __launch_bounds__(256) void hist_kernel(
    const int* __restrict__ dst, int* __restrict__ G, int nE, int B, int NB)
{
  __shared__ int h[256];
  int blk = blockIdx.x, t = threadIdx.x;
  h[t] = 0;
  __syncthreads();
  int base = blk * 8192;
  int lim = min(8192, nE - base);
  for (int i = t; i < lim; i += 256)
    atomicAdd(&h[dst[base + i] >> 9], 1);
  __syncthreads();
  if (t < NB) G[t * B + blk] = h[t];
}

// generic scan (256/block): excl-in-block + block sums
__global__ __launch_bounds__(256) void scan1_kernel(
    const int* __restrict__ in, int* __restrict__ out,
    int* __restrict__ bsum, int n)
{
  __shared__ int sh[256];
  int t = threadIdx.x;
  int i = blockIdx.x * 256 + t;
  int c = (i < n) ? in[i] : 0;
  sh[t] = c;
  __syncthreads();
#pragma unroll
  for (int off = 1; off < 256; off <<= 1) {
    int v = 0;
    if (t >= off) v = sh[t - off];
    __syncthreads();
    if (t >= off) sh[t] += v;
    __syncthreads();
  }
  if (i < n) out[i] = sh[t] - c;
  if (t == 255) bsum[blockIdx.x] = sh[255];
}

__global__ __launch_bounds__(256) void scan2_kernel(int* __restrict__ bsum, int nb)
{
  __shared__ int sh[256];
  __shared__ int carry;
  int t = threadIdx.x;
  if (t == 0) carry = 0;
  __syncthreads();
  for (int base = 0; base < nb; base += 256) {
    int i = base + t;
    int v = (i < nb) ? bsum[i] : 0;
    sh[t] = v;
    __syncthreads();
#pragma unroll
    for (int off = 1; off < 256; off <<= 1) {
      int u = 0;
      if (t >= off) u = sh[t - off];
      __syncthreads();
      if (t >= off) sh[t] += u;
      __syncthreads();
    }
    int c0 = carry;
    int incl = sh[t], total = sh[255];
    if (i < nb) bsum[i] = c0 + incl - v;
    __syncthreads();
    if (t == 0) carry = c0 + total;
    __syncthreads();
  }
  if (t == 0) bsum[nb] = carry;
}

__global__ __launch_bounds__(256) void scan3_kernel(
    int* __restrict__ W, const int* __restrict__ bsum, int NG, int nb)
{
  int i = blockIdx.x * 256 + threadIdx.x;
  if (i < NG) W[i] += bsum[i >> 8];
  else if (i == NG) W[NG] = bsum[nb];
}

// scatter edges into bucket-major pair array; block-exclusive regions
__global__ __launch_bounds__(256) void scatter2_kernel(
    const int* __restrict__ src, const int* __restrict__ dst,
    const int* __restrict__ W, int2* __restrict__ EP, int nE, int B, int NB)
{
  __shared__ int cur[256];
  int blk = blockIdx.x, t = threadIdx.x;
  if (t < NB) cur[t] = W[t * B + blk];
  __syncthreads();
  int base = blk * 8192;
  int lim = min(8192, nE - base);
  for (int i = t; i < lim; i += 256) {
    int s = src[base + i], d = dst[base + i];
    int slot = atomicAdd(&cur[d >> 9], 1);
    EP[slot] = make_int2(s, d);
  }
}

// per-bucket: cnt/offs from LDS hist+scan; adj fill in block-local window
__global__ __launch_bounds__(256) void fillc_kernel(
    const int2* __restrict__ EP, const int* __restrict__ W,
    int* __restrict__ cnt, int* __restrict__ offs, int* __restrict__ adj,
    int n, int nE, int B, int NB)
{
  __shared__ int h[512];
  int b = blockIdx.x, t = threadIdx.x;
  int segStart = W[b * B];
  int segEnd = (b == NB - 1) ? nE : W[(b + 1) * B];
  int nodeBase = b << 9;

  h[t] = 0; h[t + 256] = 0;
  __syncthreads();
  for (int i = segStart + t; i < segEnd; i += 256)
    atomicAdd(&h[EP[i].y - nodeBase], 1);
  __syncthreads();
  int c0 = h[t], c1 = h[t + 256];
#pragma unroll
  for (int off = 1; off < 512; off <<= 1) {
    int a = (t >= off) ? h[t - off] : 0;
    int bb = (t + 256 >= off) ? h[t + 256 - off] : 0;
    __syncthreads();
    h[t] += a; h[t + 256] += bb;
    __syncthreads();
  }
  int e0 = h[t] - c0, e1 = h[t + 256] - c1;   // exclusive
  int g0 = nodeBase + t, g1 = nodeBase + t + 256;
  if (g0 < n) { cnt[g0] = c0; offs[g0] = segStart + e0; }
  if (g1 < n) { cnt[g1] = c1; offs[g1] = segStart + e1; }
  if (b == 0 && t == 0) offs[n] = nE;
  __syncthreads();
  h[t] = e0; h[t + 256] = e1;                 // cursors
  __syncthreads();
  for (int i = segStart + t; i < segEnd; i += 256) {
    int2 p = EP[i];
    int slot = atomicAdd(&h[p.y - nodeBase], 1);
    adj[segStart + slot] = p.x;
  }
}

// ---------------- gather: A[d] = sum_{s in adj[d]} P[s]  (wave per node) ----
__global__ __launch_bounds__(256) void gather_kernel(
    const float* __restrict__ P, const int* __restrict__ offs,
    const int* __restrict__ adj, float* __restrict__ A, int n)
{
  int node = (blockIdx.x * 256 + threadIdx.x) >> 6;
  int lane = threadIdx.x & 63;
  if (node >= n) return;
  int beg = offs[node], end = offs[node + 1];
  float acc0 = 0.f, acc1 = 0.f;
  int j = beg;
  while (j < end) {
    int m = min(end - j, 64);
    int idx = (lane < m) ? adj[j + lane] : 0;
    int q = 0;
    for (; q + 1 < m; q += 2) {
      int s0 = __shfl(idx, q, 64);
      int s1 = __shfl(idx, q + 1, 64);
      acc0 += P[(size_t)s0 * 64 + lane];
      acc1 += P[(size_t)s1 * 64 + lane];
    }
    if (q < m) {
      int s0 = __shfl(idx, q, 64);
      acc0 += P[(size_t)s0 * 64 + lane];
    }
    j += m;
  }
  A[(size_t)node * 64 + lane] = acc0 + acc1;
}

// ---- conv3 epilogue: H4 = relu(A/deg + bc3); accumulate sum/sumsq ----------
__global__ __launch_bounds__(256) void post3_kernel(
    const float* __restrict__ A, const int* __restrict__ deg,
    const float* __restrict__ bc3, float* __restrict__ H4,
    float* __restrict__ stats, int n)
{
  int t = threadIdx.x;
  int f = t & 63, q = t >> 6;
  float b = bc3[f];
  float s = 0.f, s2 = 0.f;
  for (int node = blockIdx.x * 4 + q; node < n; node += gridDim.x * 4) {
    float v = fmaxf(A[(size_t)node * 64 + f] / fmaxf((float)deg[node], 1.f) + b, 0.f);
    H4[(size_t)node * 64 + f] = v;
    s += v; s2 += v * v;
  }
  __shared__ float red[2][4][64];
  red[0][q][f] = s; red[1][q][f] = s2;
  __syncthreads();
  if (t < 128) {
    int which = t >> 6, ff = t & 63;
    float a = red[which][0][ff] + red[which][1][ff] +
              red[which][2][ff] + red[which][3][ff];
    atomicAdd(&stats[which * 64 + ff], a);
  }
}

// ---- fold batchnorm into W2 ------------------------------------------------
__global__ __launch_bounds__(256) void fold_kernel(
    const float* __restrict__ stats, const float* __restrict__ gamma,
    const float* __restrict__ beta, const float* __restrict__ W2,
    const float* __restrict__ b2, float* __restrict__ W2f,
    float* __restrict__ b2f, int n)
{
  __shared__ float rsg[64], corr[64];
  int t = threadIdx.x;
  if (t < 64) {
    float m = stats[t] / (float)n;
    float var = stats[64 + t] / (float)n - m * m;
    float rs = rsqrtf(var + 1e-5f);
    float g = gamma[t] * rs;
    rsg[t] = g;
    corr[t] = beta[t] - m * g;
  }
  __syncthreads();
#pragma unroll
  for (int i = 0; i < 8; ++i) {
    int lin = t + i * 256;
    int k = lin >> 5;
    W2f[lin] = rsg[k] * W2[lin];
  }
  if (t < 32) {
    float a = b2[t];
    for (int k = 0; k < 64; ++k) a += corr[k] * W2[k * 32 + t];
    b2f[t] = a;
  }
}

// ---- final: out = relu(H4 @ W2f + b2f) @ W3 + b3 ---------------------------
__global__ __launch_bounds__(256) void final_kernel(
    const float* __restrict__ H4, const float* __restrict__ W2f,
    const float* __restrict__ b2f, const float* __restrict__ W3,
    const float* __restrict__ b3, float* __restrict__ Out, int n)
{
  __shared__ float Hs[64][68];
  __shared__ float W2s[64][32];
  __shared__ float W3s[32][32];
  __shared__ float Us[64][36];
  __shared__ float b2s[32], b3s[32];
  const int t = threadIdx.x;
  const int node0 = blockIdx.x * 64;

#pragma unroll
  for (int i = 0; i < 4; ++i) {
    int lin = t + i * 256;
    int node = lin >> 4, kq = lin & 15;
    float4 v = make_float4(0.f, 0.f, 0.f, 0.f);
    if (node0 + node < n)
      v = *(const float4*)&H4[(size_t)(node0 + node) * 64 + kq * 4];
    *(float4*)&Hs[node][kq * 4] = v;
  }
#pragma unroll
  for (int i = 0; i < 2; ++i) {
    int lin = t + i * 256;
    ((float4*)&W2s[0][0])[lin] = ((const float4*)W2f)[lin];
  }
  ((float4*)&W3s[0][0])[t & 255] = ((const float4*)W3)[t & 255];
  if (t < 32) { b2s[t] = b2f[t]; b3s[t] = b3[t]; }
  __syncthreads();

  const int rg = t >> 4, cg = t & 15;
  float acc[4][2] = {{0.f,0.f},{0.f,0.f},{0.f,0.f},{0.f,0.f}};
#pragma unroll 8
  for (int k = 0; k < 64; ++k) {
    float a[4] = {Hs[rg*4+0][k], Hs[rg*4+1][k], Hs[rg*4+2][k], Hs[rg*4+3][k]};
    float w0 = W2s[k][cg*2], w1 = W2s[k][cg*2+1];
#pragma unroll
    for (int i = 0; i < 4; ++i) { acc[i][0] += a[i]*w0; acc[i][1] += a[i]*w1; }
  }
#pragma unroll
  for (int i = 0; i < 4; ++i) {
    Us[rg*4+i][cg*2+0] = fmaxf(acc[i][0] + b2s[cg*2+0], 0.f);
    Us[rg*4+i][cg*2+1] = fmaxf(acc[i][1] + b2s[cg*2+1], 0.f);
  }
  __syncthreads();

  float acc2[4][2] = {{0.f,0.f},{0.f,0.f},{0.f,0.f},{0.f,0.f}};
#pragma unroll
  for (int k = 0; k < 32; ++k) {
    float a[4] = {Us[rg*4+0][k], Us[rg*4+1][k], Us[rg*4+2][k], Us[rg*4+3][k]};
    float w0 = W3s[k][cg*2], w1 = W3s[k][cg*2+1];
#pragma unroll
    for (int i = 0; i < 4; ++i) { acc2[i][0] += a[i]*w0; acc2[i][1] += a[i]*w1; }
  }
  float (*Os)[36] = (float(*)[36])Hs;
#pragma unroll
  for (int i = 0; i < 4; ++i) {
    Os[rg*4+i][cg*2+0] = acc2[i][0] + b3s[cg*2+0];
    Os[rg*4+i][cg*2+1] = acc2[i][1] + b3s[cg*2+1];
  }
  __syncthreads();
#pragma unroll
  for (int i = 0; i < 2; ++i) {
    int lin = t + i * 256;
    int node = lin >> 3, c4 = lin & 7;
    if (node0 + node < n)
      *(float4*)&Out[(size_t)(node0 + node) * 32 + c4 * 4] =
          *(float4*)&Os[node][c4 * 4];
  }
}

// ---------------------------------------------------------------------------
extern "C" void kernel_launch(void* const* d_in, const int* in_sizes, int n_in,
                              void* d_out, int out_size, void* d_ws, size_t ws_size,
                              hipStream_t stream)
{
  const float* X     = (const float*)d_in[0];
  const float* W1    = (const float*)d_in[1];
  const float* b1    = (const float*)d_in[2];
  const float* Wc1   = (const float*)d_in[3];
  const float* bc1   = (const float*)d_in[4];
  const float* Wc2   = (const float*)d_in[5];
  const float* bc2   = (const float*)d_in[6];
  const float* Wc3   = (const float*)d_in[7];
  const float* bc3   = (const float*)d_in[8];
  const float* gamma = (const float*)d_in[9];
  const float* beta  = (const float*)d_in[10];
  const float* W2    = (const float*)d_in[11];
  const float* b2    = (const float*)d_in[12];
  const float* W3    = (const float*)d_in[13];
  const float* b3    = (const float*)d_in[14];
  const int*   ei    = (const int*)d_in[15];

  const int n  = in_sizes[0] / F_IN;
  const int nE = in_sizes[15] / 2;
  const int* src  = ei;
  const int* dstv = ei + nE;

  const int NB = (n + 511) >> 9;          // buckets of 512 nodes
  const int B  = (nE + 8191) >> 13;       // chunks of 8192 edges
  const int NG = NB * B;
  const int nbG = (NG + 255) / 256;

  float* ws    = (float*)d_ws;
  float* H1    = ws;                                   // n*128 (H4 reuses)
  float* P     = H1 + (size_t)n * D_EMB;               // n*64 fp32
  float* A     = P  + (size_t)n * D_HID;               // n*64
  float* stats = A  + (size_t)n * D_HID;               // 128
  float* W2f   = stats + 128;                          // 2048
  float* b2f   = W2f + 2048;                           // 32
  int*   cnt   = (int*)(b2f + 32);                     // n
  int*   offs  = cnt + n;                              // n+1
  int*   G     = offs + n + 1;                         // NG
  int*   W     = G + NG;                               // NG+1
  int*   bsum  = W + NG + 1;                           // nbG+1
  int*   adj   = bsum + nbG + 1;                       // nE
  uintptr_t epAddr = ((uintptr_t)(adj + nE) + 7) & ~(uintptr_t)7;
  int2*  EP    = (int2*)epAddr;                        // nE pairs
  short8* Wt2  = (short8*)(EP + nE);                   // 128KB
  float* H4    = H1;                                   // reuse H1

  const int nb  = (n + 63) / 64;
  const int gatherBlocks = (int)(((long long)n * 64 + 255) / 256);

  hipMemsetAsync(stats, 0, 128 * sizeof(float), stream);

  // W1 -> fragment-linear bf16, then bf16-MFMA lin1
  wt_kernel<<<32, 256, 0, stream>>>(W1, Wt2);
  lin1_mfma_kernel<<<(n + 127) / 128, 256, 0, stream>>>(X, Wt2, b1, H1, n);

  // CSR build (bucketed, no global scatter)
  hist_kernel<<<B, 256, 0, stream>>>(dstv, G, nE, B, NB);
  scan1_kernel<<<nbG, 256, 0, stream>>>(G, W, bsum, NG);
  scan2_kernel<<<1, 256, 0, stream>>>(bsum, nbG);
  scan3_kernel<<<(NG + 256) / 256, 256, 0, stream>>>(W, bsum, NG, nbG);
  scatter2_kernel<<<B, 256, 0, stream>>>(src, dstv, W, EP, nE, B, NB);
  fillc_kernel<<<NB, 256, 0, stream>>>(EP, W, cnt, offs, adj, n, nE, B, NB);

  // conv1: P = H1 @ Wc1 ; A = gather-sum(P)
  mm_kernel<128, false><<<nb, 256, 0, stream>>>(H1, nullptr, nullptr, Wc1, P, n);
  gather_kernel<<<gatherBlocks, 256, 0, stream>>>(P, offs, adj, A, n);

  // conv2
  mm_kernel<64, true><<<nb, 256, 0, stream>>>(A, cnt, bc1, Wc2, P, n);
  gather_kernel<<<gatherBlocks, 256, 0, stream>>>(P, offs, adj, A, n);

  // conv3
  mm_kernel<64, true><<<nb, 256, 0, stream>>>(A, cnt, bc2, Wc3, P, n);
  gather_kernel<<<gatherBlocks, 256, 0, stream>>>(P, offs, adj, A, n);

  // conv3 epilogue + batch stats
  post3_kernel<<<256, 256, 0, stream>>>(A, cnt, bc3, H4, stats, n);

  // fold batchnorm into W2, then fused lin2+lin3
  fold_kernel<<<1, 256, 0, stream>>>(stats, gamma, beta, W2, b2, W2f, b2f, n);
  final_kernel<<<nb, 256, 0, stream>>>(H4, W2f, b2f, W3, b3, (float*)d_out, n);
}